// Round 12
// baseline (1628.137 us; speedup 1.0000x reference)
//
#include <hip/hip_runtime.h>

typedef __attribute__((ext_vector_type(8))) short bf16x8_t;
typedef __attribute__((ext_vector_type(4))) short bf16x4_t;
typedef __attribute__((ext_vector_type(4))) float f32x4_t;

constexpr int NG = 16;
constexpr float EPS = 1e-5f;

__device__ inline unsigned short f2bf(float f) {
  unsigned u = __builtin_bit_cast(unsigned, f);
  u += 0x7FFFu + ((u >> 16) & 1u);
  return (unsigned short)(u >> 16);
}
__device__ inline float bf2f(unsigned short u) {
  unsigned x = ((unsigned)u) << 16;
  return __builtin_bit_cast(float, x);
}

// load 8 contiguous elements as f32 from fp32 or bf16 storage
template<bool F32>
__device__ inline void ldrow8(const void* base, size_t off, float v[8]) {
  if constexpr (F32) {
    const float* p = (const float*)base + off;
    float4 f0 = *(const float4*)p, f1 = *(const float4*)(p + 4);
    v[0]=f0.x; v[1]=f0.y; v[2]=f0.z; v[3]=f0.w;
    v[4]=f1.x; v[5]=f1.y; v[6]=f1.z; v[7]=f1.w;
  } else {
    bf16x8_t t = *(const bf16x8_t*)((const unsigned short*)base + off);
#pragma unroll
    for (int k = 0; k < 8; ++k) v[k] = bf2f((unsigned short)t[k]);
  }
}

// =====================================================================
// Dense partial GEMM over nodes (coalesced):
//   P[n] = x[n] @ [Wne_s | Wne_d | Wnmp_s | Wnmp_d]  (N x 384 bf16, swizzled)
// =====================================================================
__global__ __launch_bounds__(256) void k_dense_x(
    const float* __restrict__ x,
    const unsigned short* __restrict__ WtNE,   // [64][320]
    const unsigned short* __restrict__ WtNM,   // [128][320]
    unsigned short* __restrict__ P, int nN)
{
  int gw = (int)((blockIdx.x * 256u + threadIdx.x) >> 6);
  int ntile = nN >> 4;
  if (gw >= ntile) return;
  int lane = threadIdx.x & 63;
  int colb = lane & 15;
  int ko = (lane >> 4) << 3;
  int rowb = (lane >> 4) << 2;
  int row = (gw << 4) + colb;
  const float* xr = x + (size_t)row * 128;
  f32x4_t a1[4] = {}, a2[4] = {}, a3[8] = {}, a4[8] = {};
#pragma unroll
  for (int c = 0; c < 4; ++c) {
    float4 f0 = *(const float4*)(xr + c * 32 + ko);
    float4 f1 = *(const float4*)(xr + c * 32 + ko + 4);
    float vv[8] = {f0.x,f0.y,f0.z,f0.w,f1.x,f1.y,f1.z,f1.w};
    bf16x8_t a;
#pragma unroll
    for (int k = 0; k < 8; ++k) a[k] = (short)f2bf(vv[k]);
#pragma unroll
    for (int nb = 0; nb < 4; ++nb) {
      bf16x8_t b1 = *(const bf16x8_t*)(WtNE + (size_t)(nb * 16 + colb) * 320 + c * 32 + ko);
      a1[nb] = __builtin_amdgcn_mfma_f32_16x16x32_bf16(a, b1, a1[nb], 0, 0, 0);
      bf16x8_t b2 = *(const bf16x8_t*)(WtNE + (size_t)(nb * 16 + colb) * 320 + (c + 4) * 32 + ko);
      a2[nb] = __builtin_amdgcn_mfma_f32_16x16x32_bf16(a, b2, a2[nb], 0, 0, 0);
    }
#pragma unroll
    for (int nb = 0; nb < 8; ++nb) {
      bf16x8_t b3 = *(const bf16x8_t*)(WtNM + (size_t)(nb * 16 + colb) * 320 + c * 32 + ko);
      a3[nb] = __builtin_amdgcn_mfma_f32_16x16x32_bf16(a, b3, a3[nb], 0, 0, 0);
      bf16x8_t b4 = *(const bf16x8_t*)(WtNM + (size_t)(nb * 16 + colb) * 320 + (c + 4) * 32 + ko);
      a4[nb] = __builtin_amdgcn_mfma_f32_16x16x32_bf16(a, b4, a4[nb], 0, 0, 0);
    }
  }
#pragma unroll
  for (int r = 0; r < 4; ++r) {
    size_t ro = (size_t)((gw << 4) + rowb + r) * 384;
    bf16x4_t t1, t2;
#pragma unroll
    for (int nb = 0; nb < 4; ++nb) { t1[nb] = (short)f2bf(a1[nb][r]); t2[nb] = (short)f2bf(a2[nb][r]); }
    *(bf16x4_t*)(P + ro + colb * 4) = t1;
    *(bf16x4_t*)(P + ro + 64 + colb * 4) = t2;
    bf16x8_t t3, t4;
#pragma unroll
    for (int nb = 0; nb < 8; ++nb) { t3[nb] = (short)f2bf(a3[nb][r]); t4[nb] = (short)f2bf(a4[nb][r]); }
    *(bf16x8_t*)(P + ro + 128 + colb * 8) = t3;
    *(bf16x8_t*)(P + ro + 256 + colb * 8) = t4;
  }
}

// =====================================================================
// Dense angle+emp partials over edges (coalesced, one eAB read):
//   ê = affE1(e);  PA1=ê@Wea_s, PA2=ê@Wea_d, PE3=ê@Wemp_s, PE4=ê@Wemp_d
// PAE row (256 shorts), DE-INTERLEAVED 128B blocks:
//   [0..63]=PA1, [64..127]=PE3, [128..191]=PA2, [192..255]=PE4
// (each block: pos colb*4+nb). k_angle touches only PA lines; k_fin_emp only PE.
// =====================================================================
__global__ __launch_bounds__(256) void k_prep_e(
    const unsigned short* __restrict__ eA, const int* __restrict__ ebatch,
    const float* __restrict__ afA, const float* __restrict__ afB,
    const unsigned short* __restrict__ WtA,    // wt_ea  [64][192]
    const unsigned short* __restrict__ WtP,    // wt_emp [64][192]
    unsigned short* __restrict__ PAE, int nE)
{
  __shared__ float lA[1024], lB[1024];
  for (int i = threadIdx.x; i < 1024; i += 256) { lA[i] = afA[i]; lB[i] = afB[i]; }
  __syncthreads();
  int gw = (int)((blockIdx.x * 256u + threadIdx.x) >> 6);
  int ntile = nE >> 4;
  if (gw >= ntile) return;
  int lane = threadIdx.x & 63;
  int colb = lane & 15;
  int ko = (lane >> 4) << 3;
  int rowb = (lane >> 4) << 2;
  int row = (gw << 4) + colb;
  int ge = ebatch[row];
  f32x4_t pa1[4] = {}, pa2[4] = {}, pe3[4] = {}, pe4[4] = {};
#pragma unroll
  for (int c2 = 0; c2 < 2; ++c2) {
    int fb = c2 * 32 + ko;
    bf16x8_t t = *(const bf16x8_t*)(eA + (size_t)row * 64 + fb);
    bf16x8_t an;
#pragma unroll
    for (int k = 0; k < 8; ++k)
      an[k] = (short)f2bf(bf2f((unsigned short)t[k]) * lA[ge*64 + fb + k] + lB[ge*64 + fb + k]);
#pragma unroll
    for (int nb = 0; nb < 4; ++nb) {
      size_t wb = (size_t)(nb * 16 + colb) * 192;
      bf16x8_t b;
      b = *(const bf16x8_t*)(WtA + wb + c2 * 32 + ko);
      pa1[nb] = __builtin_amdgcn_mfma_f32_16x16x32_bf16(an, b, pa1[nb], 0, 0, 0);
      b = *(const bf16x8_t*)(WtA + wb + 64 + c2 * 32 + ko);
      pa2[nb] = __builtin_amdgcn_mfma_f32_16x16x32_bf16(an, b, pa2[nb], 0, 0, 0);
      b = *(const bf16x8_t*)(WtP + wb + c2 * 32 + ko);
      pe3[nb] = __builtin_amdgcn_mfma_f32_16x16x32_bf16(an, b, pe3[nb], 0, 0, 0);
      b = *(const bf16x8_t*)(WtP + wb + 64 + c2 * 32 + ko);
      pe4[nb] = __builtin_amdgcn_mfma_f32_16x16x32_bf16(an, b, pe4[nb], 0, 0, 0);
    }
  }
#pragma unroll
  for (int r = 0; r < 4; ++r) {
    size_t ro = (size_t)((gw << 4) + rowb + r) * 256;
    bf16x4_t t1, t3, t2, t4;
#pragma unroll
    for (int nb = 0; nb < 4; ++nb) {
      t1[nb] = (short)f2bf(pa1[nb][r]); t3[nb] = (short)f2bf(pe3[nb][r]);
      t2[nb] = (short)f2bf(pa2[nb][r]); t4[nb] = (short)f2bf(pe4[nb][r]);
    }
    *(bf16x4_t*)(PAE + ro + colb * 4) = t1;          // PA1
    *(bf16x4_t*)(PAE + ro + 64 + colb * 4) = t3;     // PE3
    *(bf16x4_t*)(PAE + ro + 128 + colb * 4) = t2;    // PA2
    *(bf16x4_t*)(PAE + ro + 192 + colb * 4) = t4;    // PE4
  }
}

// =====================================================================
// EDGE stage: e_out(bf16) = ê + P_T1[s]+P_T2[d] + ê@Wne_e + b  (+stats)
// =====================================================================
template<bool EF32>
__global__ __launch_bounds__(256) void k_edge(
    const unsigned short* __restrict__ P, const void* e_in, unsigned short* e_out,
    const int* __restrict__ ei, const int* __restrict__ ebatch,
    const unsigned short* __restrict__ Wt,    // wt_ne [64][320]
    const float* __restrict__ bias,
    const float* __restrict__ afA, const float* __restrict__ afB,
    float* __restrict__ gs1, float* __restrict__ gs2, int nE)
{
  __shared__ float lA[1024], lB[1024];
  __shared__ float ls1[NG], ls2[NG];
  __shared__ __align__(16) unsigned short tl[4][16][72];  // per-wave normalized tile
  for (int i = threadIdx.x; i < 1024; i += 256) { lA[i] = afA[i]; lB[i] = afB[i]; }
  if (threadIdx.x < NG) { ls1[threadIdx.x] = 0.f; ls2[threadIdx.x] = 0.f; }
  __syncthreads();
  int gw = (int)((blockIdx.x * 256u + threadIdx.x) >> 6);
  int ntile = nE >> 4;
  bool act = gw < ntile;
  int lane = threadIdx.x & 63;
  int wid = threadIdx.x >> 6;
  int colb = lane & 15;
  int ko = (lane >> 4) << 3;
  int rowb = (lane >> 4) << 2;
  float sr[4] = {0.f,0.f,0.f,0.f}, ssr[4] = {0.f,0.f,0.f,0.f};
  if (act) {
    int sI[4], dI[4];
#pragma unroll
    for (int r = 0; r < 4; ++r) {
      int e_r = (gw << 4) + rowb + r;
      sI[r] = ei[e_r]; dI[r] = ei[nE + e_r];
    }
    bf16x4_t g1[4], g2[4];
#pragma unroll
    for (int r = 0; r < 4; ++r) {
      g1[r] = *(const bf16x4_t*)(P + (size_t)sI[r] * 384 + colb * 4);
      g2[r] = *(const bf16x4_t*)(P + (size_t)dI[r] * 384 + 64 + colb * 4);
    }
    int row = (gw << 4) + colb;
    int ge = ebatch[row];
    f32x4_t acc[4] = {};
#pragma unroll
    for (int c2 = 0; c2 < 2; ++c2) {
      int fb = c2 * 32 + ko;
      float vv[8];
      ldrow8<EF32>(e_in, (size_t)row * 64 + fb, vv);
      bf16x8_t a;
#pragma unroll
      for (int k = 0; k < 8; ++k) a[k] = (short)f2bf(vv[k] * lA[ge*64 + fb + k] + lB[ge*64 + fb + k]);
      *(bf16x8_t*)&tl[wid][colb][fb] = a;
#pragma unroll
      for (int nb = 0; nb < 4; ++nb) {
        bf16x8_t b = *(const bf16x8_t*)(Wt + (size_t)(nb * 16 + colb) * 320 + (8 + c2) * 32 + ko);
        acc[nb] = __builtin_amdgcn_mfma_f32_16x16x32_bf16(a, b, acc[nb], 0, 0, 0);
      }
    }
#pragma unroll
    for (int r = 0; r < 4; ++r) {
      int e_ = (gw << 4) + rowb + r;
#pragma unroll
      for (int nb = 0; nb < 4; ++nb) {
        int col = nb * 16 + colb;
        size_t off = (size_t)e_ * 64 + col;
        float nv = bf2f(tl[wid][rowb + r][col]);
        float vv = nv + bias[col]
                 + acc[nb][r] + bf2f((unsigned short)g1[r][nb]) + bf2f((unsigned short)g2[r][nb]);
        e_out[off] = f2bf(vv);
        sr[r] += vv; ssr[r] += vv * vv;
      }
    }
  }
#pragma unroll
  for (int m = 1; m <= 8; m <<= 1)
#pragma unroll
    for (int r = 0; r < 4; ++r) { sr[r] += __shfl_xor(sr[r], m); ssr[r] += __shfl_xor(ssr[r], m); }
  if (act && colb == 0) {
#pragma unroll
    for (int r = 0; r < 4; ++r) {
      int g = ebatch[(gw << 4) + rowb + r];
      atomicAdd(&ls1[g], sr[r]); atomicAdd(&ls2[g], ssr[r]);
    }
  }
  __syncthreads();
  if (threadIdx.x < NG) {
    atomicAdd(&gs1[threadIdx.x], ls1[threadIdx.x]);
    atomicAdd(&gs2[threadIdx.x], ls2[threadIdx.x]);
  }
}

// =====================================================================
// ANGLE stage: gathers only PA1/PA2 (one 128B line per side per angle).
//   a_out(bf16) = â + PA1[s]+PA2[d] + â@Wea_a + b (+stats); no pe output.
// =====================================================================
template<bool AF32>
__global__ __launch_bounds__(256) void k_angle(
    const unsigned short* __restrict__ PAE,
    const void* a_in, unsigned short* a_out,
    const int* __restrict__ ti, const int* __restrict__ abatch,
    const unsigned short* __restrict__ Wt,    // wt_ea [64][192]
    const float* __restrict__ bias,
    const float* __restrict__ afAA, const float* __restrict__ afAB,
    float* __restrict__ gs1, float* __restrict__ gs2, int nA)
{
  __shared__ float lAA[1024], lAB[1024];
  __shared__ float ls1[NG], ls2[NG];
  __shared__ __align__(16) unsigned short tl[4][16][72];
  for (int i = threadIdx.x; i < 1024; i += 256) { lAA[i] = afAA[i]; lAB[i] = afAB[i]; }
  if (threadIdx.x < NG) { ls1[threadIdx.x] = 0.f; ls2[threadIdx.x] = 0.f; }
  __syncthreads();
  int gw = (int)((blockIdx.x * 256u + threadIdx.x) >> 6);
  int ntile = nA >> 4;
  bool act = gw < ntile;
  int lane = threadIdx.x & 63;
  int wid = threadIdx.x >> 6;
  int colb = lane & 15;
  int ko = (lane >> 4) << 3;
  int rowb = (lane >> 4) << 2;
  float sr[4] = {0.f,0.f,0.f,0.f}, ssr[4] = {0.f,0.f,0.f,0.f};
  if (act) {
    int sI[4], dI[4];
#pragma unroll
    for (int r = 0; r < 4; ++r) {
      int a_r = (gw << 4) + rowb + r;
      sI[r] = ti[a_r]; dI[r] = ti[nA + a_r];
    }
    bf16x4_t gS[4], gD[4];
#pragma unroll
    for (int r = 0; r < 4; ++r) {
      gS[r] = *(const bf16x4_t*)(PAE + (size_t)sI[r] * 256 + colb * 4);          // PA1
      gD[r] = *(const bf16x4_t*)(PAE + (size_t)dI[r] * 256 + 128 + colb * 4);    // PA2
    }
    int row = (gw << 4) + colb;
    int ga = abatch[row];
    f32x4_t acc[4] = {};
#pragma unroll
    for (int c2 = 0; c2 < 2; ++c2) {
      int fb = c2 * 32 + ko;
      float vv[8];
      ldrow8<AF32>(a_in, (size_t)row * 64 + fb, vv);
      bf16x8_t a;
#pragma unroll
      for (int k = 0; k < 8; ++k) a[k] = (short)f2bf(vv[k] * lAA[ga*64 + fb + k] + lAB[ga*64 + fb + k]);
      *(bf16x8_t*)&tl[wid][colb][fb] = a;
#pragma unroll
      for (int nb = 0; nb < 4; ++nb) {
        bf16x8_t b = *(const bf16x8_t*)(Wt + (size_t)(nb * 16 + colb) * 192 + 128 + c2 * 32 + ko);
        acc[nb] = __builtin_amdgcn_mfma_f32_16x16x32_bf16(a, b, acc[nb], 0, 0, 0);
      }
    }
#pragma unroll
    for (int r = 0; r < 4; ++r) {
      int a_ = (gw << 4) + rowb + r;
#pragma unroll
      for (int nb = 0; nb < 4; ++nb) {
        int col = nb * 16 + colb;
        size_t off = (size_t)a_ * 64 + col;
        float nv = bf2f(tl[wid][rowb + r][col]);
        float vv = nv + bias[col] + acc[nb][r]
                 + bf2f((unsigned short)gS[r][nb]) + bf2f((unsigned short)gD[r][nb]);
        a_out[off] = f2bf(vv);
        sr[r] += vv; ssr[r] += vv * vv;
      }
    }
  }
#pragma unroll
  for (int m = 1; m <= 8; m <<= 1)
#pragma unroll
    for (int r = 0; r < 4; ++r) { sr[r] += __shfl_xor(sr[r], m); ssr[r] += __shfl_xor(ssr[r], m); }
  if (act && colb == 0) {
#pragma unroll
    for (int r = 0; r < 4; ++r) {
      int g = abatch[(gw << 4) + rowb + r];
      atomicAdd(&ls1[g], sr[r]); atomicAdd(&ls2[g], ssr[r]);
    }
  }
  __syncthreads();
  if (threadIdx.x < NG) {
    atomicAdd(&gs1[threadIdx.x], ls1[threadIdx.x]);
    atomicAdd(&gs2[threadIdx.x], ls2[threadIdx.x]);
  }
}

// =====================================================================
// emp finish: gathers PE3[s]/PE4[d] from PAE directly (pe round trip deleted):
//   msg = relu(PE3[s] + PE4[d] + affA1(a1)@Wemp_a + b)
// =====================================================================
__global__ __launch_bounds__(256) void k_fin_emp(
    const unsigned short* __restrict__ PAE,
    const unsigned short* __restrict__ a_, const int* __restrict__ ti,
    const int* __restrict__ abatch,
    const unsigned short* __restrict__ Wt,    // wt_emp [64][192]
    const float* __restrict__ bias,
    const float* __restrict__ afAA, const float* __restrict__ afAB,
    unsigned short* __restrict__ msg, int nA)
{
  __shared__ float lAA[1024], lAB[1024];
  for (int i = threadIdx.x; i < 1024; i += 256) { lAA[i] = afAA[i]; lAB[i] = afAB[i]; }
  __syncthreads();
  int gw = (int)((blockIdx.x * 256u + threadIdx.x) >> 6);
  int ntile = nA >> 4;
  if (gw >= ntile) return;
  int lane = threadIdx.x & 63;
  int colb = lane & 15;
  int ko = (lane >> 4) << 3;
  int rowb = (lane >> 4) << 2;
  // gathers first (8 independent 8B loads)
  int sI[4], dI[4];
#pragma unroll
  for (int r = 0; r < 4; ++r) {
    int a_r = (gw << 4) + rowb + r;
    sI[r] = ti[a_r]; dI[r] = ti[nA + a_r];
  }
  bf16x4_t g3[4], g4[4];
#pragma unroll
  for (int r = 0; r < 4; ++r) {
    g3[r] = *(const bf16x4_t*)(PAE + (size_t)sI[r] * 256 + 64 + colb * 4);     // PE3
    g4[r] = *(const bf16x4_t*)(PAE + (size_t)dI[r] * 256 + 192 + colb * 4);    // PE4
  }
  int row = (gw << 4) + colb;
  int ga = abatch[row];
  f32x4_t acc[4] = {};
#pragma unroll
  for (int c2 = 0; c2 < 2; ++c2) {
    int fb = c2 * 32 + ko;
    bf16x8_t t = *(const bf16x8_t*)(a_ + (size_t)row * 64 + fb);
    bf16x8_t a;
#pragma unroll
    for (int k = 0; k < 8; ++k)
      a[k] = (short)f2bf(bf2f((unsigned short)t[k]) * lAA[ga*64 + fb + k] + lAB[ga*64 + fb + k]);
#pragma unroll
    for (int nb = 0; nb < 4; ++nb) {
      bf16x8_t b = *(const bf16x8_t*)(Wt + (size_t)(nb * 16 + colb) * 192 + 128 + c2 * 32 + ko);
      acc[nb] = __builtin_amdgcn_mfma_f32_16x16x32_bf16(a, b, acc[nb], 0, 0, 0);
    }
  }
#pragma unroll
  for (int r = 0; r < 4; ++r) {
    int a_idx = (gw << 4) + rowb + r;
#pragma unroll
    for (int nb = 0; nb < 4; ++nb) {
      int col = nb * 16 + colb;
      float v = fmaxf(acc[nb][r] + bf2f((unsigned short)g3[r][nb]) + bf2f((unsigned short)g4[r][nb])
                      + bias[col], 0.f);
      msg[(size_t)a_idx * 64 + col] = f2bf(v);
    }
  }
}

// =====================================================================
// nmp finish (gathers T3/T4 of P directly):
//   msg = relu(P_T3[s] + P_T4[d] + affE2(e2)@Wnmp_e + b)
// =====================================================================
__global__ __launch_bounds__(256) void k_fin_nmp(
    const unsigned short* __restrict__ P,
    const unsigned short* __restrict__ e, const int* __restrict__ ei,
    const int* __restrict__ ebatch,
    const unsigned short* __restrict__ Wt,    // wt_nmp [128][320]
    const float* __restrict__ bias,
    const float* __restrict__ afEA, const float* __restrict__ afEB,
    unsigned short* __restrict__ msg, int nE)
{
  __shared__ float lEA[1024], lEB[1024];
  for (int i = threadIdx.x; i < 1024; i += 256) { lEA[i] = afEA[i]; lEB[i] = afEB[i]; }
  __syncthreads();
  int gw = (int)((blockIdx.x * 256u + threadIdx.x) >> 6);
  int ntile = nE >> 4;
  if (gw >= ntile) return;
  int lane = threadIdx.x & 63;
  int colb = lane & 15;
  int ko = (lane >> 4) << 3;
  int rowb = (lane >> 4) << 2;
  int sI[4], dI[4];
#pragma unroll
  for (int r = 0; r < 4; ++r) {
    int e_r = (gw << 4) + rowb + r;
    sI[r] = ei[e_r]; dI[r] = ei[nE + e_r];
  }
  bf16x8_t g3[4], g4[4];
#pragma unroll
  for (int r = 0; r < 4; ++r) {
    g3[r] = *(const bf16x8_t*)(P + (size_t)sI[r] * 384 + 128 + colb * 8);
    g4[r] = *(const bf16x8_t*)(P + (size_t)dI[r] * 384 + 256 + colb * 8);
  }
  int row = (gw << 4) + colb;
  int ge = ebatch[row];
  f32x4_t acc[8] = {};
#pragma unroll
  for (int c2 = 0; c2 < 2; ++c2) {
    int fb = c2 * 32 + ko;
    bf16x8_t t = *(const bf16x8_t*)(e + (size_t)row * 64 + fb);
    bf16x8_t a;
#pragma unroll
    for (int k = 0; k < 8; ++k)
      a[k] = (short)f2bf(bf2f((unsigned short)t[k]) * lEA[ge*64 + fb + k] + lEB[ge*64 + fb + k]);
#pragma unroll
    for (int nb = 0; nb < 8; ++nb) {
      bf16x8_t b = *(const bf16x8_t*)(Wt + (size_t)(nb * 16 + colb) * 320 + (8 + c2) * 32 + ko);
      acc[nb] = __builtin_amdgcn_mfma_f32_16x16x32_bf16(a, b, acc[nb], 0, 0, 0);
    }
  }
#pragma unroll
  for (int r = 0; r < 4; ++r) {
    int e_ = (gw << 4) + rowb + r;
#pragma unroll
    for (int nb = 0; nb < 8; ++nb) {
      int col = nb * 16 + colb;
      float v = fmaxf(acc[nb][r] + bf2f((unsigned short)g3[r][nb]) + bf2f((unsigned short)g4[r][nb])
                      + bias[col], 0.f);
      msg[(size_t)e_ * 128 + col] = f2bf(v);
    }
  }
}

// =====================================================================
// CSR gather-reduce over edges: e2(bf16) = affE1(e1) + sum(msg rows); fused stats.
// =====================================================================
__global__ __launch_bounds__(256) void k_red_e(
    const unsigned short* __restrict__ msg, const unsigned short* e_in, unsigned short* e_out,
    const int* __restrict__ ptr, const int* __restrict__ perm,
    const int* __restrict__ ebatch,
    const float* __restrict__ afA, const float* __restrict__ afB,
    float* __restrict__ gs1, float* __restrict__ gs2, int nE)
{
  __shared__ float lA[1024], lB[1024], ls1[NG], ls2[NG];
  for (int i = threadIdx.x; i < 1024; i += 256) { lA[i] = afA[i]; lB[i] = afB[i]; }
  if (threadIdx.x < NG) { ls1[threadIdx.x] = 0.f; ls2[threadIdx.x] = 0.f; }
  __syncthreads();
  int lane = threadIdx.x & 63;
  int wv = (int)((blockIdx.x * 256u + threadIdx.x) >> 6);
  int nw = (int)((gridDim.x * 256u) >> 6);
  for (int eidx = wv; eidx < nE; eidx += nw) {
    int p0 = ptr[eidx], p1 = ptr[eidx + 1];
    float sum = 0.f;
    for (int j = p0; j < p1; ++j) {
      int aidx = perm[j];
      sum += bf2f(msg[(size_t)aidx * 64 + lane]);
    }
    int g = ebatch[eidx];
    size_t off = (size_t)eidx * 64 + lane;
    float v = bf2f(e_in[off]) * lA[g*64 + lane] + lB[g*64 + lane] + sum;
    e_out[off] = f2bf(v);
    float s = v, ss = v * v;
#pragma unroll
    for (int m = 1; m < 64; m <<= 1) { s += __shfl_xor(s, m); ss += __shfl_xor(ss, m); }
    if (lane == 0) { atomicAdd(&ls1[g], s); atomicAdd(&ls2[g], ss); }
  }
  __syncthreads();
  if (threadIdx.x < NG) {
    atomicAdd(&gs1[threadIdx.x], ls1[threadIdx.x]);
    atomicAdd(&gs2[threadIdx.x], ls2[threadIdx.x]);
  }
}

// =====================================================================
// CSR gather-reduce over nodes: h = x + sum(msg rows); fused stats. (x fp32)
// =====================================================================
__global__ __launch_bounds__(256) void k_red_n(
    const unsigned short* __restrict__ msg, const float* x_in, float* out,
    const int* __restrict__ ptr, const int* __restrict__ perm,
    const int* __restrict__ nbatch,
    float* __restrict__ gs1, float* __restrict__ gs2, int nN)
{
  __shared__ float ls1[NG], ls2[NG];
  if (threadIdx.x < NG) { ls1[threadIdx.x] = 0.f; ls2[threadIdx.x] = 0.f; }
  __syncthreads();
  int lane = threadIdx.x & 63;
  int wv = (int)((blockIdx.x * 256u + threadIdx.x) >> 6);
  int nw = (int)((gridDim.x * 256u) >> 6);
  for (int n = wv; n < nN; n += nw) {
    int p0 = ptr[n], p1 = ptr[n + 1];
    float s0 = 0.f, s1v = 0.f;
    for (int j = p0; j < p1; ++j) {
      int e = perm[j];
      unsigned u = *(const unsigned*)(msg + (size_t)e * 128 + lane * 2);
      s0 += bf2f((unsigned short)(u & 0xffffu));
      s1v += bf2f((unsigned short)(u >> 16));
    }
    size_t off = (size_t)n * 128 + lane * 2;
    float h0 = x_in[off] + s0, h1 = x_in[off + 1] + s1v;
    out[off] = h0; out[off + 1] = h1;
    float s = h0 + h1, ss = h0 * h0 + h1 * h1;
#pragma unroll
    for (int m = 1; m < 64; m <<= 1) { s += __shfl_xor(s, m); ss += __shfl_xor(ss, m); }
    if (lane == 0) { int g = nbatch[n]; atomicAdd(&ls1[g], s); atomicAdd(&ls2[g], ss); }
  }
  __syncthreads();
  if (threadIdx.x < NG) {
    atomicAdd(&gs1[threadIdx.x], ls1[threadIdx.x]);
    atomicAdd(&gs2[threadIdx.x], ls2[threadIdx.x]);
  }
}

// ---- affine table construction ----
__global__ __launch_bounds__(256) void k_mkaff(
    const float* __restrict__ s1, const float* __restrict__ s2,
    const float* __restrict__ cnt, int F,
    const float* __restrict__ w, const float* __restrict__ b,
    float* __restrict__ A, float* __restrict__ B)
{
  int idx = blockIdx.x * 256 + threadIdx.x;
  if (idx >= NG * F) return;
  int g = idx / F, f = idx - g * F;
  float norm = fmaxf(cnt[g], 1.f) * (float)F;
  float m = s1[g] / norm;
  float var = s2[g] / norm - m * m;
  float inv = rsqrtf(var + EPS);
  float a = inv * w[f];
  A[idx] = a;
  B[idx] = b[f] - m * a;
}

__global__ __launch_bounds__(256) void k_idaff(float* __restrict__ A, float* __restrict__ B, int n)
{
  int idx = blockIdx.x * 256 + threadIdx.x;
  if (idx < n) { A[idx] = 1.f; B[idx] = 0.f; }
}

// ---- apply norm to x (in-place, fp32) ----
__global__ __launch_bounds__(256) void k_apply(
    float* h, const int* __restrict__ batch,
    const float* __restrict__ A, const float* __restrict__ B, int nN)
{
  int total = nN * 16;
  int stride = gridDim.x * 256;
  for (int idx = blockIdx.x * 256 + threadIdx.x; idx < total; idx += stride) {
    int row = idx >> 4, q = (idx & 15) * 8;
    int g = batch[row];
    float* hp = h + (size_t)row * 128 + q;
    float4 f0 = *(const float4*)hp;
    float4 f1 = *(const float4*)(hp + 4);
    float vv[8] = {f0.x,f0.y,f0.z,f0.w,f1.x,f1.y,f1.z,f1.w};
#pragma unroll
    for (int k = 0; k < 8; ++k) vv[k] = vv[k] * A[(g << 7) + q + k] + B[(g << 7) + q + k];
    float4 g0 = {vv[0],vv[1],vv[2],vv[3]}, g1 = {vv[4],vv[5],vv[6],vv[7]};
    *(float4*)hp = g0;
    *(float4*)(hp + 4) = g1;
  }
}

__global__ __launch_bounds__(256) void k_count(
    const int* __restrict__ batch, int n, float* __restrict__ cnt)
{
  __shared__ float lc[NG];
  if (threadIdx.x < NG) lc[threadIdx.x] = 0.f;
  __syncthreads();
  for (int i = blockIdx.x * 256 + threadIdx.x; i < n; i += gridDim.x * 256)
    atomicAdd(&lc[batch[i]], 1.f);
  __syncthreads();
  if (threadIdx.x < NG) atomicAdd(&cnt[threadIdx.x], lc[threadIdx.x]);
}

// ---- CSR build ----
__global__ __launch_bounds__(256) void k_hist(
    const int* __restrict__ dst, int n, int* __restrict__ cnt)
{
  for (int i = blockIdx.x * 256 + threadIdx.x; i < n; i += gridDim.x * 256)
    atomicAdd(&cnt[dst[i]], 1);
}

__global__ __launch_bounds__(256) void k_scan1(
    const int* __restrict__ in, int* __restrict__ out, int* __restrict__ bsum, int n)
{
  __shared__ int wtot[4];
  int tid = threadIdx.x, lane = tid & 63, wid = tid >> 6;
  int base = blockIdx.x * 1024 + tid * 4;
  int v[4];
#pragma unroll
  for (int k = 0; k < 4; ++k) v[k] = (base + k < n) ? in[base + k] : 0;
  int tsum = v[0] + v[1] + v[2] + v[3];
  int incl = tsum;
#pragma unroll
  for (int off = 1; off < 64; off <<= 1) {
    int up = __shfl_up(incl, off);
    if (lane >= off) incl += up;
  }
  if (lane == 63) wtot[wid] = incl;
  __syncthreads();
  if (tid == 0) {
    int r = 0;
#pragma unroll
    for (int w2 = 0; w2 < 4; ++w2) { int t = wtot[w2]; wtot[w2] = r; r += t; }
    bsum[blockIdx.x] = r;
  }
  __syncthreads();
  int excl = wtot[wid] + incl - tsum;
#pragma unroll
  for (int k = 0; k < 4; ++k) {
    if (base + k < n) out[base + k] = excl;
    excl += v[k];
  }
}

__global__ __launch_bounds__(256) void k_scan2(int* __restrict__ bsum, int nb, int* __restrict__ total_out)
{
  __shared__ int wtot[4];
  int tid = threadIdx.x, lane = tid & 63, wid = tid >> 6;
  int base = tid * 4;
  int v[4];
#pragma unroll
  for (int k = 0; k < 4; ++k) v[k] = (base + k < nb) ? bsum[base + k] : 0;
  int tsum = v[0] + v[1] + v[2] + v[3];
  int incl = tsum;
#pragma unroll
  for (int off = 1; off < 64; off <<= 1) {
    int up = __shfl_up(incl, off);
    if (lane >= off) incl += up;
  }
  if (lane == 63) wtot[wid] = incl;
  __syncthreads();
  if (tid == 0) {
    int r = 0;
#pragma unroll
    for (int w2 = 0; w2 < 4; ++w2) { int t = wtot[w2]; wtot[w2] = r; r += t; }
    *total_out = r;
  }
  __syncthreads();
  int excl = wtot[wid] + incl - tsum;
#pragma unroll
  for (int k = 0; k < 4; ++k) {
    if (base + k < nb) bsum[base + k] = excl;
    excl += v[k];
  }
}

__global__ __launch_bounds__(256) void k_scan3(
    int* __restrict__ ptr, int* __restrict__ cur, const int* __restrict__ bsum, int n)
{
  for (int i = blockIdx.x * 256 + threadIdx.x; i < n; i += gridDim.x * 256) {
    int v = ptr[i] + bsum[i >> 10];
    ptr[i] = v; cur[i] = v;
  }
}

__global__ __launch_bounds__(256) void k_scatter(
    const int* __restrict__ dst, int* __restrict__ cur, int* __restrict__ perm, int n)
{
  for (int i = blockIdx.x * 256 + threadIdx.x; i < n; i += gridDim.x * 256) {
    int d = dst[i];
    int p = atomicAdd(&cur[d], 1);
    perm[p] = i;
  }
}

// ---- weight prep ----
__global__ __launch_bounds__(256) void k_wt(
    const float* __restrict__ W, unsigned short* __restrict__ Wt, int K, int NO)
{
  int idx = blockIdx.x * 256 + threadIdx.x;
  if (idx >= K * NO) return;
  int k = idx / NO, j = idx - k * NO;
  Wt[(size_t)j * K + k] = f2bf(W[idx]);
}

extern "C" void kernel_launch(void* const* d_in, const int* in_sizes, int n_in,
                              void* d_out, int out_size, void* d_ws, size_t ws_size,
                              hipStream_t stream)
{
  const float* x0    = (const float*)d_in[0];
  const float* e0    = (const float*)d_in[1];
  const float* a0    = (const float*)d_in[2];
  const float* W_ne  = (const float*)d_in[3];
  const float* b_ne  = (const float*)d_in[4];
  const float* g_e   = (const float*)d_in[5];
  const float* be_e  = (const float*)d_in[6];
  const float* W_ea  = (const float*)d_in[7];
  const float* b_ea  = (const float*)d_in[8];
  const float* g_a   = (const float*)d_in[9];
  const float* be_a  = (const float*)d_in[10];
  const float* W_emp = (const float*)d_in[11];
  const float* b_emp = (const float*)d_in[12];
  const float* g_emp = (const float*)d_in[13];
  const float* be_emp= (const float*)d_in[14];
  const float* W_nmp = (const float*)d_in[15];
  const float* b_nmp = (const float*)d_in[16];
  const float* g_nmp = (const float*)d_in[17];
  const float* be_nmp= (const float*)d_in[18];
  const int* node_batch  = (const int*)d_in[19];
  const int* edge_index  = (const int*)d_in[20];
  const int* edge_batch  = (const int*)d_in[21];
  const int* tb_index    = (const int*)d_in[22];
  const int* angle_batch = (const int*)d_in[23];

  const int N = in_sizes[0] / 128;
  const int E = in_sizes[1] / 64;
  const int A = in_sizes[2] / 64;

  // ---- workspace layout (bytes, 256-aligned) ----
  char* wsp = (char*)d_ws;
  auto alloc = [&](size_t bytes) { char* p = wsp; wsp += (bytes + 255) & ~(size_t)255; return p; };
  unsigned short* eAB  = (unsigned short*)alloc((size_t)E * 64 * 2);   // e intermediate (bf16)
  unsigned short* aAB  = (unsigned short*)alloc((size_t)A * 64 * 2);   // a intermediate (bf16)
  unsigned short* msg  = (unsigned short*)alloc((size_t)A * 64 * 2);   // msg_e / msg_n
  unsigned short* P    = (unsigned short*)alloc((size_t)N * 384 * 2);  // x partials (lives to stage 4)
  unsigned short* PAE  = (unsigned short*)alloc((size_t)E * 256 * 2);  // angle+emp partials (de-interleaved)
  int* ptr_n  = (int*)alloc((size_t)(N + 1) * 4);
  int* cur_n  = (int*)alloc((size_t)N * 4);
  int* perm_n = (int*)alloc((size_t)E * 4);
  int* ptr_e  = (int*)alloc((size_t)(E + 1) * 4);
  int* cur_e  = (int*)alloc((size_t)E * 4);
  int* perm_e = (int*)alloc((size_t)A * 4);
  int* bsum   = (int*)alloc(4096 * 4);
  float* stats = (float*)alloc(5 * NG * 4);   // contiguous: s1,s2,cnt_n,cnt_e,cnt_a
  float* s1    = stats;
  float* s2    = stats + NG;
  float* cnt_n = stats + 2 * NG;
  float* cnt_e = stats + 3 * NG;
  float* cnt_a = stats + 4 * NG;
  float* afE_idA = (float*)alloc(1024 * 4); float* afE_idB = (float*)alloc(1024 * 4);
  float* afA_idA = (float*)alloc(1024 * 4); float* afA_idB = (float*)alloc(1024 * 4);
  float* afE1A   = (float*)alloc(1024 * 4); float* afE1B   = (float*)alloc(1024 * 4);
  float* afE2A   = (float*)alloc(1024 * 4); float* afE2B   = (float*)alloc(1024 * 4);
  float* afA1A   = (float*)alloc(1024 * 4); float* afA1B   = (float*)alloc(1024 * 4);
  float* afXA    = (float*)alloc(2048 * 4); float* afXB    = (float*)alloc(2048 * 4);
  unsigned short* wt_ne  = (unsigned short*)alloc((size_t)2 * 320 * 64 * 2);
  unsigned short* wt_ea  = (unsigned short*)alloc((size_t)2 * 192 * 64 * 2);
  unsigned short* wt_emp = (unsigned short*)alloc((size_t)2 * 192 * 64 * 2);
  unsigned short* wt_nmp = (unsigned short*)alloc((size_t)2 * 320 * 128 * 2);

  float* x_out = (float*)d_out;

  // ---- one-time prep ----
  for (int i = 0; i < 2; ++i) {
    k_wt<<<(320*64 + 255)/256, 256, 0, stream>>>(W_ne  + (size_t)i*320*64,  wt_ne  + (size_t)i*320*64,  320, 64);
    k_wt<<<(192*64 + 255)/256, 256, 0, stream>>>(W_ea  + (size_t)i*192*64,  wt_ea  + (size_t)i*192*64,  192, 64);
    k_wt<<<(192*64 + 255)/256, 256, 0, stream>>>(W_emp + (size_t)i*192*64,  wt_emp + (size_t)i*192*64,  192, 64);
    k_wt<<<(320*128 + 255)/256, 256, 0, stream>>>(W_nmp + (size_t)i*320*128, wt_nmp + (size_t)i*320*128, 320, 128);
  }
  hipMemsetAsync(stats, 0, 5 * NG * 4, stream);
  k_count<<<512, 256, 0, stream>>>(node_batch, N, cnt_n);
  k_count<<<512, 256, 0, stream>>>(edge_batch, E, cnt_e);
  k_count<<<512, 256, 0, stream>>>(angle_batch, A, cnt_a);
  k_idaff<<<4, 256, 0, stream>>>(afE_idA, afE_idB, 1024);
  k_idaff<<<4, 256, 0, stream>>>(afA_idA, afA_idB, 1024);

  // CSR over nodes (dst of edge_index) and edges (dst of threebody)
  hipMemsetAsync(cur_n, 0, (size_t)N * 4, stream);
  hipMemsetAsync(cur_e, 0, (size_t)E * 4, stream);
  k_hist<<<1024, 256, 0, stream>>>(edge_index + E, E, cur_n);
  k_hist<<<1024, 256, 0, stream>>>(tb_index + A, A, cur_e);
  int nbN = (N + 1023) / 1024, nbE = (E + 1023) / 1024;
  k_scan1<<<nbN, 256, 0, stream>>>(cur_n, ptr_n, bsum, N);
  k_scan2<<<1, 256, 0, stream>>>(bsum, nbN, ptr_n + N);
  k_scan3<<<1024, 256, 0, stream>>>(ptr_n, cur_n, bsum, N);
  k_scatter<<<1024, 256, 0, stream>>>(edge_index + E, cur_n, perm_n, E);
  k_scan1<<<nbE, 256, 0, stream>>>(cur_e, ptr_e, bsum, E);
  k_scan2<<<1, 256, 0, stream>>>(bsum, nbE, ptr_e + E);
  k_scan3<<<1024, 256, 0, stream>>>(ptr_e, cur_e, bsum, E);
  k_scatter<<<1024, 256, 0, stream>>>(tb_index + A, cur_e, perm_e, A);

  const float* x_cur = x0;
  int blkE = (E / 16 + 3) / 4;
  int blkA = (A / 16 + 3) / 4;
  int blkN = (N / 16 + 3) / 4;

  for (int i = 0; i < 2; ++i) {
    const float* fEinA = (i == 0) ? afE_idA : afE2A;
    const float* fEinB = (i == 0) ? afE_idB : afE2B;
    const float* fAinA = (i == 0) ? afA_idA : afA1A;
    const float* fAinB = (i == 0) ? afA_idB : afA1B;

    // 0. dense x-partials (P persists through stage 4)
    k_dense_x<<<blkN, 256, 0, stream>>>(x_cur, wt_ne + (size_t)i*320*64,
                                        wt_nmp + (size_t)i*320*128, P, N);

    // 1. edge stage -> affE1
    hipMemsetAsync(s1, 0, 2 * NG * 4, stream);
    if (i == 0)
      k_edge<true><<<blkE, 256, 0, stream>>>(P, (const void*)e0, eAB, edge_index, edge_batch,
                                             wt_ne + (size_t)i*320*64, b_ne + i*64,
                                             fEinA, fEinB, s1, s2, E);
    else
      k_edge<false><<<blkE, 256, 0, stream>>>(P, (const void*)eAB, eAB, edge_index, edge_batch,
                                              wt_ne + (size_t)i*320*64, b_ne + i*64,
                                              fEinA, fEinB, s1, s2, E);
    k_mkaff<<<4, 256, 0, stream>>>(s1, s2, cnt_e, 64, g_e + i*64, be_e + i*64, afE1A, afE1B);

    // 1.5 dense angle+emp partials -> PAE (de-interleaved)
    k_prep_e<<<blkE, 256, 0, stream>>>(eAB, edge_batch, afE1A, afE1B,
                                       wt_ea + (size_t)i*192*64, wt_emp + (size_t)i*192*64,
                                       PAE, E);

    // 2. angle stage (PA gathers only; no pe) -> affA1
    hipMemsetAsync(s1, 0, 2 * NG * 4, stream);
    if (i == 0)
      k_angle<true><<<blkA, 256, 0, stream>>>(PAE, (const void*)a0, aAB, tb_index, angle_batch,
                                              wt_ea + (size_t)i*192*64, b_ea + i*64,
                                              fAinA, fAinB, s1, s2, A);
    else
      k_angle<false><<<blkA, 256, 0, stream>>>(PAE, (const void*)aAB, aAB, tb_index, angle_batch,
                                               wt_ea + (size_t)i*192*64, b_ea + i*64,
                                               fAinA, fAinB, s1, s2, A);
    k_mkaff<<<4, 256, 0, stream>>>(s1, s2, cnt_a, 64, g_a + i*64, be_a + i*64, afA1A, afA1B);

    // 3. emp finish (gathers PE3/PE4 directly) -> msg; CSR reduce -> affE2
    k_fin_emp<<<blkA, 256, 0, stream>>>(PAE, aAB, tb_index, angle_batch,
                                        wt_emp + (size_t)i*192*64, b_emp + i*64,
                                        afA1A, afA1B, msg, A);
    hipMemsetAsync(s1, 0, 2 * NG * 4, stream);
    k_red_e<<<2048, 256, 0, stream>>>(msg, eAB, eAB, ptr_e, perm_e, edge_batch,
                                      afE1A, afE1B, s1, s2, E);
    k_mkaff<<<4, 256, 0, stream>>>(s1, s2, cnt_e, 64, g_emp + i*64, be_emp + i*64, afE2A, afE2B);

    // 4. nmp finish (gathers P T3/T4 directly) -> msg; CSR reduce; apply
    k_fin_nmp<<<blkE, 256, 0, stream>>>(P, eAB, edge_index, edge_batch,
                                        wt_nmp + (size_t)i*320*128, b_nmp + i*128,
                                        afE2A, afE2B, msg, E);
    hipMemsetAsync(s1, 0, 2 * NG * 4, stream);
    k_red_n<<<2048, 256, 0, stream>>>(msg, x_cur, x_out, ptr_n, perm_n, node_batch,
                                      s1, s2, N);
    k_mkaff<<<8, 256, 0, stream>>>(s1, s2, cnt_n, 128, g_nmp + i*128, be_nmp + i*128, afXA, afXB);
    k_apply<<<2048, 256, 0, stream>>>(x_out, node_batch, afXA, afXB, N);

    x_cur = x_out;
  }
}

// Round 13
// 1584.610 us; speedup vs baseline: 1.0275x; 1.0275x over previous
//
#include <hip/hip_runtime.h>

typedef __attribute__((ext_vector_type(8))) short bf16x8_t;
typedef __attribute__((ext_vector_type(4))) short bf16x4_t;
typedef __attribute__((ext_vector_type(4))) float f32x4_t;

constexpr int NG = 16;
constexpr float EPS = 1e-5f;

__device__ inline unsigned short f2bf(float f) {
  unsigned u = __builtin_bit_cast(unsigned, f);
  u += 0x7FFFu + ((u >> 16) & 1u);
  return (unsigned short)(u >> 16);
}
__device__ inline float bf2f(unsigned short u) {
  unsigned x = ((unsigned)u) << 16;
  return __builtin_bit_cast(float, x);
}

// load 8 contiguous elements as f32 from fp32 or bf16 storage
template<bool F32>
__device__ inline void ldrow8(const void* base, size_t off, float v[8]) {
  if constexpr (F32) {
    const float* p = (const float*)base + off;
    float4 f0 = *(const float4*)p, f1 = *(const float4*)(p + 4);
    v[0]=f0.x; v[1]=f0.y; v[2]=f0.z; v[3]=f0.w;
    v[4]=f1.x; v[5]=f1.y; v[6]=f1.z; v[7]=f1.w;
  } else {
    bf16x8_t t = *(const bf16x8_t*)((const unsigned short*)base + off);
#pragma unroll
    for (int k = 0; k < 8; ++k) v[k] = bf2f((unsigned short)t[k]);
  }
}

// =====================================================================
// Dense partial GEMM over nodes (coalesced):
//   P[n] = x[n] @ [Wne_s | Wne_d | Wnmp_s | Wnmp_d]  (N x 384 bf16, swizzled)
// =====================================================================
__global__ __launch_bounds__(256) void k_dense_x(
    const float* __restrict__ x,
    const unsigned short* __restrict__ WtNE,   // [64][320]
    const unsigned short* __restrict__ WtNM,   // [128][320]
    unsigned short* __restrict__ P, int nN)
{
  int gw = (int)((blockIdx.x * 256u + threadIdx.x) >> 6);
  int ntile = nN >> 4;
  if (gw >= ntile) return;
  int lane = threadIdx.x & 63;
  int colb = lane & 15;
  int ko = (lane >> 4) << 3;
  int rowb = (lane >> 4) << 2;
  int row = (gw << 4) + colb;
  const float* xr = x + (size_t)row * 128;
  f32x4_t a1[4] = {}, a2[4] = {}, a3[8] = {}, a4[8] = {};
#pragma unroll
  for (int c = 0; c < 4; ++c) {
    float4 f0 = *(const float4*)(xr + c * 32 + ko);
    float4 f1 = *(const float4*)(xr + c * 32 + ko + 4);
    float vv[8] = {f0.x,f0.y,f0.z,f0.w,f1.x,f1.y,f1.z,f1.w};
    bf16x8_t a;
#pragma unroll
    for (int k = 0; k < 8; ++k) a[k] = (short)f2bf(vv[k]);
#pragma unroll
    for (int nb = 0; nb < 4; ++nb) {
      bf16x8_t b1 = *(const bf16x8_t*)(WtNE + (size_t)(nb * 16 + colb) * 320 + c * 32 + ko);
      a1[nb] = __builtin_amdgcn_mfma_f32_16x16x32_bf16(a, b1, a1[nb], 0, 0, 0);
      bf16x8_t b2 = *(const bf16x8_t*)(WtNE + (size_t)(nb * 16 + colb) * 320 + (c + 4) * 32 + ko);
      a2[nb] = __builtin_amdgcn_mfma_f32_16x16x32_bf16(a, b2, a2[nb], 0, 0, 0);
    }
#pragma unroll
    for (int nb = 0; nb < 8; ++nb) {
      bf16x8_t b3 = *(const bf16x8_t*)(WtNM + (size_t)(nb * 16 + colb) * 320 + c * 32 + ko);
      a3[nb] = __builtin_amdgcn_mfma_f32_16x16x32_bf16(a, b3, a3[nb], 0, 0, 0);
      bf16x8_t b4 = *(const bf16x8_t*)(WtNM + (size_t)(nb * 16 + colb) * 320 + (c + 4) * 32 + ko);
      a4[nb] = __builtin_amdgcn_mfma_f32_16x16x32_bf16(a, b4, a4[nb], 0, 0, 0);
    }
  }
#pragma unroll
  for (int r = 0; r < 4; ++r) {
    size_t ro = (size_t)((gw << 4) + rowb + r) * 384;
    bf16x4_t t1, t2;
#pragma unroll
    for (int nb = 0; nb < 4; ++nb) { t1[nb] = (short)f2bf(a1[nb][r]); t2[nb] = (short)f2bf(a2[nb][r]); }
    *(bf16x4_t*)(P + ro + colb * 4) = t1;
    *(bf16x4_t*)(P + ro + 64 + colb * 4) = t2;
    bf16x8_t t3, t4;
#pragma unroll
    for (int nb = 0; nb < 8; ++nb) { t3[nb] = (short)f2bf(a3[nb][r]); t4[nb] = (short)f2bf(a4[nb][r]); }
    *(bf16x8_t*)(P + ro + 128 + colb * 8) = t3;
    *(bf16x8_t*)(P + ro + 256 + colb * 8) = t4;
  }
}

// =====================================================================
// Dense angle+emp partials over edges (coalesced, one eAB read):
//   ê = affE1(e);  PA1=ê@Wea_s, PA2=ê@Wea_d, PE3=ê@Wemp_s, PE4=ê@Wemp_d
// PAE row (256 shorts), de-interleaved 128B blocks:
//   [0..63]=PA1, [64..127]=PE3, [128..191]=PA2, [192..255]=PE4
// =====================================================================
__global__ __launch_bounds__(256) void k_prep_e(
    const unsigned short* __restrict__ eA, const int* __restrict__ ebatch,
    const float* __restrict__ afA, const float* __restrict__ afB,
    const unsigned short* __restrict__ WtA,    // wt_ea  [64][192]
    const unsigned short* __restrict__ WtP,    // wt_emp [64][192]
    unsigned short* __restrict__ PAE, int nE)
{
  __shared__ float lA[1024], lB[1024];
  for (int i = threadIdx.x; i < 1024; i += 256) { lA[i] = afA[i]; lB[i] = afB[i]; }
  __syncthreads();
  int gw = (int)((blockIdx.x * 256u + threadIdx.x) >> 6);
  int ntile = nE >> 4;
  if (gw >= ntile) return;
  int lane = threadIdx.x & 63;
  int colb = lane & 15;
  int ko = (lane >> 4) << 3;
  int rowb = (lane >> 4) << 2;
  int row = (gw << 4) + colb;
  int ge = ebatch[row];
  f32x4_t pa1[4] = {}, pa2[4] = {}, pe3[4] = {}, pe4[4] = {};
#pragma unroll
  for (int c2 = 0; c2 < 2; ++c2) {
    int fb = c2 * 32 + ko;
    bf16x8_t t = *(const bf16x8_t*)(eA + (size_t)row * 64 + fb);
    bf16x8_t an;
#pragma unroll
    for (int k = 0; k < 8; ++k)
      an[k] = (short)f2bf(bf2f((unsigned short)t[k]) * lA[ge*64 + fb + k] + lB[ge*64 + fb + k]);
#pragma unroll
    for (int nb = 0; nb < 4; ++nb) {
      size_t wb = (size_t)(nb * 16 + colb) * 192;
      bf16x8_t b;
      b = *(const bf16x8_t*)(WtA + wb + c2 * 32 + ko);
      pa1[nb] = __builtin_amdgcn_mfma_f32_16x16x32_bf16(an, b, pa1[nb], 0, 0, 0);
      b = *(const bf16x8_t*)(WtA + wb + 64 + c2 * 32 + ko);
      pa2[nb] = __builtin_amdgcn_mfma_f32_16x16x32_bf16(an, b, pa2[nb], 0, 0, 0);
      b = *(const bf16x8_t*)(WtP + wb + c2 * 32 + ko);
      pe3[nb] = __builtin_amdgcn_mfma_f32_16x16x32_bf16(an, b, pe3[nb], 0, 0, 0);
      b = *(const bf16x8_t*)(WtP + wb + 64 + c2 * 32 + ko);
      pe4[nb] = __builtin_amdgcn_mfma_f32_16x16x32_bf16(an, b, pe4[nb], 0, 0, 0);
    }
  }
#pragma unroll
  for (int r = 0; r < 4; ++r) {
    size_t ro = (size_t)((gw << 4) + rowb + r) * 256;
    bf16x4_t t1, t3, t2, t4;
#pragma unroll
    for (int nb = 0; nb < 4; ++nb) {
      t1[nb] = (short)f2bf(pa1[nb][r]); t3[nb] = (short)f2bf(pe3[nb][r]);
      t2[nb] = (short)f2bf(pa2[nb][r]); t4[nb] = (short)f2bf(pe4[nb][r]);
    }
    *(bf16x4_t*)(PAE + ro + colb * 4) = t1;          // PA1
    *(bf16x4_t*)(PAE + ro + 64 + colb * 4) = t3;     // PE3
    *(bf16x4_t*)(PAE + ro + 128 + colb * 4) = t2;    // PA2
    *(bf16x4_t*)(PAE + ro + 192 + colb * 4) = t4;    // PE4
  }
}

// =====================================================================
// EDGE stage: e_out(bf16) = ê + P_T1[s]+P_T2[d] + ê@Wne_e + b  (+stats)
// =====================================================================
template<bool EF32>
__global__ __launch_bounds__(256) void k_edge(
    const unsigned short* __restrict__ P, const void* e_in, unsigned short* e_out,
    const int* __restrict__ ei, const int* __restrict__ ebatch,
    const unsigned short* __restrict__ Wt,    // wt_ne [64][320]
    const float* __restrict__ bias,
    const float* __restrict__ afA, const float* __restrict__ afB,
    float* __restrict__ gs1, float* __restrict__ gs2, int nE)
{
  __shared__ float lA[1024], lB[1024];
  __shared__ float ls1[NG], ls2[NG];
  __shared__ __align__(16) unsigned short tl[4][16][72];
  for (int i = threadIdx.x; i < 1024; i += 256) { lA[i] = afA[i]; lB[i] = afB[i]; }
  if (threadIdx.x < NG) { ls1[threadIdx.x] = 0.f; ls2[threadIdx.x] = 0.f; }
  __syncthreads();
  int gw = (int)((blockIdx.x * 256u + threadIdx.x) >> 6);
  int ntile = nE >> 4;
  bool act = gw < ntile;
  int lane = threadIdx.x & 63;
  int wid = threadIdx.x >> 6;
  int colb = lane & 15;
  int ko = (lane >> 4) << 3;
  int rowb = (lane >> 4) << 2;
  float sr[4] = {0.f,0.f,0.f,0.f}, ssr[4] = {0.f,0.f,0.f,0.f};
  if (act) {
    int sI[4], dI[4];
#pragma unroll
    for (int r = 0; r < 4; ++r) {
      int e_r = (gw << 4) + rowb + r;
      sI[r] = ei[e_r]; dI[r] = ei[nE + e_r];
    }
    bf16x4_t g1[4], g2[4];
#pragma unroll
    for (int r = 0; r < 4; ++r) {
      g1[r] = *(const bf16x4_t*)(P + (size_t)sI[r] * 384 + colb * 4);
      g2[r] = *(const bf16x4_t*)(P + (size_t)dI[r] * 384 + 64 + colb * 4);
    }
    int row = (gw << 4) + colb;
    int ge = ebatch[row];
    f32x4_t acc[4] = {};
#pragma unroll
    for (int c2 = 0; c2 < 2; ++c2) {
      int fb = c2 * 32 + ko;
      float vv[8];
      ldrow8<EF32>(e_in, (size_t)row * 64 + fb, vv);
      bf16x8_t a;
#pragma unroll
      for (int k = 0; k < 8; ++k) a[k] = (short)f2bf(vv[k] * lA[ge*64 + fb + k] + lB[ge*64 + fb + k]);
      *(bf16x8_t*)&tl[wid][colb][fb] = a;
#pragma unroll
      for (int nb = 0; nb < 4; ++nb) {
        bf16x8_t b = *(const bf16x8_t*)(Wt + (size_t)(nb * 16 + colb) * 320 + (8 + c2) * 32 + ko);
        acc[nb] = __builtin_amdgcn_mfma_f32_16x16x32_bf16(a, b, acc[nb], 0, 0, 0);
      }
    }
#pragma unroll
    for (int r = 0; r < 4; ++r) {
      int e_ = (gw << 4) + rowb + r;
#pragma unroll
      for (int nb = 0; nb < 4; ++nb) {
        int col = nb * 16 + colb;
        size_t off = (size_t)e_ * 64 + col;
        float nv = bf2f(tl[wid][rowb + r][col]);
        float vv = nv + bias[col]
                 + acc[nb][r] + bf2f((unsigned short)g1[r][nb]) + bf2f((unsigned short)g2[r][nb]);
        e_out[off] = f2bf(vv);
        sr[r] += vv; ssr[r] += vv * vv;
      }
    }
  }
#pragma unroll
  for (int m = 1; m <= 8; m <<= 1)
#pragma unroll
    for (int r = 0; r < 4; ++r) { sr[r] += __shfl_xor(sr[r], m); ssr[r] += __shfl_xor(ssr[r], m); }
  if (act && colb == 0) {
#pragma unroll
    for (int r = 0; r < 4; ++r) {
      int g = ebatch[(gw << 4) + rowb + r];
      atomicAdd(&ls1[g], sr[r]); atomicAdd(&ls2[g], ssr[r]);
    }
  }
  __syncthreads();
  if (threadIdx.x < NG) {
    atomicAdd(&gs1[threadIdx.x], ls1[threadIdx.x]);
    atomicAdd(&gs2[threadIdx.x], ls2[threadIdx.x]);
  }
}

// =====================================================================
// ANGLE stage: gathers only PA1/PA2.
//   a_out(bf16) = â + PA1[s]+PA2[d] + â@Wea_a + b (+stats)
// =====================================================================
template<bool AF32>
__global__ __launch_bounds__(256) void k_angle(
    const unsigned short* __restrict__ PAE,
    const void* a_in, unsigned short* a_out,
    const int* __restrict__ ti, const int* __restrict__ abatch,
    const unsigned short* __restrict__ Wt,    // wt_ea [64][192]
    const float* __restrict__ bias,
    const float* __restrict__ afAA, const float* __restrict__ afAB,
    float* __restrict__ gs1, float* __restrict__ gs2, int nA)
{
  __shared__ float lAA[1024], lAB[1024];
  __shared__ float ls1[NG], ls2[NG];
  __shared__ __align__(16) unsigned short tl[4][16][72];
  for (int i = threadIdx.x; i < 1024; i += 256) { lAA[i] = afAA[i]; lAB[i] = afAB[i]; }
  if (threadIdx.x < NG) { ls1[threadIdx.x] = 0.f; ls2[threadIdx.x] = 0.f; }
  __syncthreads();
  int gw = (int)((blockIdx.x * 256u + threadIdx.x) >> 6);
  int ntile = nA >> 4;
  bool act = gw < ntile;
  int lane = threadIdx.x & 63;
  int wid = threadIdx.x >> 6;
  int colb = lane & 15;
  int ko = (lane >> 4) << 3;
  int rowb = (lane >> 4) << 2;
  float sr[4] = {0.f,0.f,0.f,0.f}, ssr[4] = {0.f,0.f,0.f,0.f};
  if (act) {
    int sI[4], dI[4];
#pragma unroll
    for (int r = 0; r < 4; ++r) {
      int a_r = (gw << 4) + rowb + r;
      sI[r] = ti[a_r]; dI[r] = ti[nA + a_r];
    }
    bf16x4_t gS[4], gD[4];
#pragma unroll
    for (int r = 0; r < 4; ++r) {
      gS[r] = *(const bf16x4_t*)(PAE + (size_t)sI[r] * 256 + colb * 4);          // PA1
      gD[r] = *(const bf16x4_t*)(PAE + (size_t)dI[r] * 256 + 128 + colb * 4);    // PA2
    }
    int row = (gw << 4) + colb;
    int ga = abatch[row];
    f32x4_t acc[4] = {};
#pragma unroll
    for (int c2 = 0; c2 < 2; ++c2) {
      int fb = c2 * 32 + ko;
      float vv[8];
      ldrow8<AF32>(a_in, (size_t)row * 64 + fb, vv);
      bf16x8_t a;
#pragma unroll
      for (int k = 0; k < 8; ++k) a[k] = (short)f2bf(vv[k] * lAA[ga*64 + fb + k] + lAB[ga*64 + fb + k]);
      *(bf16x8_t*)&tl[wid][colb][fb] = a;
#pragma unroll
      for (int nb = 0; nb < 4; ++nb) {
        bf16x8_t b = *(const bf16x8_t*)(Wt + (size_t)(nb * 16 + colb) * 192 + 128 + c2 * 32 + ko);
        acc[nb] = __builtin_amdgcn_mfma_f32_16x16x32_bf16(a, b, acc[nb], 0, 0, 0);
      }
    }
#pragma unroll
    for (int r = 0; r < 4; ++r) {
      int a_ = (gw << 4) + rowb + r;
#pragma unroll
      for (int nb = 0; nb < 4; ++nb) {
        int col = nb * 16 + colb;
        size_t off = (size_t)a_ * 64 + col;
        float nv = bf2f(tl[wid][rowb + r][col]);
        float vv = nv + bias[col] + acc[nb][r]
                 + bf2f((unsigned short)gS[r][nb]) + bf2f((unsigned short)gD[r][nb]);
        a_out[off] = f2bf(vv);
        sr[r] += vv; ssr[r] += vv * vv;
      }
    }
  }
#pragma unroll
  for (int m = 1; m <= 8; m <<= 1)
#pragma unroll
    for (int r = 0; r < 4; ++r) { sr[r] += __shfl_xor(sr[r], m); ssr[r] += __shfl_xor(ssr[r], m); }
  if (act && colb == 0) {
#pragma unroll
    for (int r = 0; r < 4; ++r) {
      int g = abatch[(gw << 4) + rowb + r];
      atomicAdd(&ls1[g], sr[r]); atomicAdd(&ls2[g], ssr[r]);
    }
  }
  __syncthreads();
  if (threadIdx.x < NG) {
    atomicAdd(&gs1[threadIdx.x], ls1[threadIdx.x]);
    atomicAdd(&gs2[threadIdx.x], ls2[threadIdx.x]);
  }
}

// =====================================================================
// emp finish: gathers PE3[s]/PE4[d]; writes msg in CSR ORDER (opos) so the
// reduce kernel streams contiguously. Scattered writes = fire-and-forget.
//   msg[opos[a]] = relu(PE3[s]+PE4[d] + affA1(a1)@Wemp_a + b)
// =====================================================================
__global__ __launch_bounds__(256) void k_fin_emp(
    const unsigned short* __restrict__ PAE,
    const unsigned short* __restrict__ a_, const int* __restrict__ ti,
    const int* __restrict__ abatch, const int* __restrict__ opos,
    const unsigned short* __restrict__ Wt,    // wt_emp [64][192]
    const float* __restrict__ bias,
    const float* __restrict__ afAA, const float* __restrict__ afAB,
    unsigned short* __restrict__ msg, int nA)
{
  __shared__ float lAA[1024], lAB[1024];
  for (int i = threadIdx.x; i < 1024; i += 256) { lAA[i] = afAA[i]; lAB[i] = afAB[i]; }
  __syncthreads();
  int gw = (int)((blockIdx.x * 256u + threadIdx.x) >> 6);
  int ntile = nA >> 4;
  if (gw >= ntile) return;
  int lane = threadIdx.x & 63;
  int colb = lane & 15;
  int ko = (lane >> 4) << 3;
  int rowb = (lane >> 4) << 2;
  int sI[4], dI[4], wr[4];
#pragma unroll
  for (int r = 0; r < 4; ++r) {
    int a_r = (gw << 4) + rowb + r;
    sI[r] = ti[a_r]; dI[r] = ti[nA + a_r]; wr[r] = opos[a_r];
  }
  bf16x4_t g3[4], g4[4];
#pragma unroll
  for (int r = 0; r < 4; ++r) {
    g3[r] = *(const bf16x4_t*)(PAE + (size_t)sI[r] * 256 + 64 + colb * 4);     // PE3
    g4[r] = *(const bf16x4_t*)(PAE + (size_t)dI[r] * 256 + 192 + colb * 4);    // PE4
  }
  int row = (gw << 4) + colb;
  int ga = abatch[row];
  f32x4_t acc[4] = {};
#pragma unroll
  for (int c2 = 0; c2 < 2; ++c2) {
    int fb = c2 * 32 + ko;
    bf16x8_t t = *(const bf16x8_t*)(a_ + (size_t)row * 64 + fb);
    bf16x8_t a;
#pragma unroll
    for (int k = 0; k < 8; ++k)
      a[k] = (short)f2bf(bf2f((unsigned short)t[k]) * lAA[ga*64 + fb + k] + lAB[ga*64 + fb + k]);
#pragma unroll
    for (int nb = 0; nb < 4; ++nb) {
      bf16x8_t b = *(const bf16x8_t*)(Wt + (size_t)(nb * 16 + colb) * 192 + 128 + c2 * 32 + ko);
      acc[nb] = __builtin_amdgcn_mfma_f32_16x16x32_bf16(a, b, acc[nb], 0, 0, 0);
    }
  }
#pragma unroll
  for (int r = 0; r < 4; ++r) {
#pragma unroll
    for (int nb = 0; nb < 4; ++nb) {
      int col = nb * 16 + colb;
      float v = fmaxf(acc[nb][r] + bf2f((unsigned short)g3[r][nb]) + bf2f((unsigned short)g4[r][nb])
                      + bias[col], 0.f);
      msg[(size_t)wr[r] * 64 + col] = f2bf(v);
    }
  }
}

// =====================================================================
// nmp finish: gathers P T3/T4; writes msg in CSR ORDER (opos).
//   msg[opos[e]] = relu(P_T3[s]+P_T4[d] + affE2(e2)@Wnmp_e + b)
// =====================================================================
__global__ __launch_bounds__(256) void k_fin_nmp(
    const unsigned short* __restrict__ P,
    const unsigned short* __restrict__ e, const int* __restrict__ ei,
    const int* __restrict__ ebatch, const int* __restrict__ opos,
    const unsigned short* __restrict__ Wt,    // wt_nmp [128][320]
    const float* __restrict__ bias,
    const float* __restrict__ afEA, const float* __restrict__ afEB,
    unsigned short* __restrict__ msg, int nE)
{
  __shared__ float lEA[1024], lEB[1024];
  for (int i = threadIdx.x; i < 1024; i += 256) { lEA[i] = afEA[i]; lEB[i] = afEB[i]; }
  __syncthreads();
  int gw = (int)((blockIdx.x * 256u + threadIdx.x) >> 6);
  int ntile = nE >> 4;
  if (gw >= ntile) return;
  int lane = threadIdx.x & 63;
  int colb = lane & 15;
  int ko = (lane >> 4) << 3;
  int rowb = (lane >> 4) << 2;
  int sI[4], dI[4], wr[4];
#pragma unroll
  for (int r = 0; r < 4; ++r) {
    int e_r = (gw << 4) + rowb + r;
    sI[r] = ei[e_r]; dI[r] = ei[nE + e_r]; wr[r] = opos[e_r];
  }
  bf16x8_t g3[4], g4[4];
#pragma unroll
  for (int r = 0; r < 4; ++r) {
    g3[r] = *(const bf16x8_t*)(P + (size_t)sI[r] * 384 + 128 + colb * 8);
    g4[r] = *(const bf16x8_t*)(P + (size_t)dI[r] * 384 + 256 + colb * 8);
  }
  int row = (gw << 4) + colb;
  int ge = ebatch[row];
  f32x4_t acc[8] = {};
#pragma unroll
  for (int c2 = 0; c2 < 2; ++c2) {
    int fb = c2 * 32 + ko;
    bf16x8_t t = *(const bf16x8_t*)(e + (size_t)row * 64 + fb);
    bf16x8_t a;
#pragma unroll
    for (int k = 0; k < 8; ++k)
      a[k] = (short)f2bf(bf2f((unsigned short)t[k]) * lEA[ge*64 + fb + k] + lEB[ge*64 + fb + k]);
#pragma unroll
    for (int nb = 0; nb < 8; ++nb) {
      bf16x8_t b = *(const bf16x8_t*)(Wt + (size_t)(nb * 16 + colb) * 320 + (8 + c2) * 32 + ko);
      acc[nb] = __builtin_amdgcn_mfma_f32_16x16x32_bf16(a, b, acc[nb], 0, 0, 0);
    }
  }
#pragma unroll
  for (int r = 0; r < 4; ++r) {
#pragma unroll
    for (int nb = 0; nb < 8; ++nb) {
      int col = nb * 16 + colb;
      float v = fmaxf(acc[nb][r] + bf2f((unsigned short)g3[r][nb]) + bf2f((unsigned short)g4[r][nb])
                      + bias[col], 0.f);
      msg[(size_t)wr[r] * 128 + col] = f2bf(v);
    }
  }
}

// =====================================================================
// CSR reduce over edges (STREAMING — msg pre-sorted in CSR order):
//   e2(bf16) = affE1(e1) + sum_{j=p0..p1} msg[j]; fused stats.
// =====================================================================
__global__ __launch_bounds__(256) void k_red_e(
    const unsigned short* __restrict__ msg, const unsigned short* e_in, unsigned short* e_out,
    const int* __restrict__ ptr, const int* __restrict__ ebatch,
    const float* __restrict__ afA, const float* __restrict__ afB,
    float* __restrict__ gs1, float* __restrict__ gs2, int nE)
{
  __shared__ float lA[1024], lB[1024], ls1[NG], ls2[NG];
  for (int i = threadIdx.x; i < 1024; i += 256) { lA[i] = afA[i]; lB[i] = afB[i]; }
  if (threadIdx.x < NG) { ls1[threadIdx.x] = 0.f; ls2[threadIdx.x] = 0.f; }
  __syncthreads();
  int lane = threadIdx.x & 63;
  int wv = (int)((blockIdx.x * 256u + threadIdx.x) >> 6);
  int nw = (int)((gridDim.x * 256u) >> 6);
  for (int eidx = wv; eidx < nE; eidx += nw) {
    int p0 = ptr[eidx], p1 = ptr[eidx + 1];
    float sum = 0.f;
    for (int j = p0; j < p1; ++j)
      sum += bf2f(msg[(size_t)j * 64 + lane]);
    int g = ebatch[eidx];
    size_t off = (size_t)eidx * 64 + lane;
    float v = bf2f(e_in[off]) * lA[g*64 + lane] + lB[g*64 + lane] + sum;
    e_out[off] = f2bf(v);
    float s = v, ss = v * v;
#pragma unroll
    for (int m = 1; m < 64; m <<= 1) { s += __shfl_xor(s, m); ss += __shfl_xor(ss, m); }
    if (lane == 0) { atomicAdd(&ls1[g], s); atomicAdd(&ls2[g], ss); }
  }
  __syncthreads();
  if (threadIdx.x < NG) {
    atomicAdd(&gs1[threadIdx.x], ls1[threadIdx.x]);
    atomicAdd(&gs2[threadIdx.x], ls2[threadIdx.x]);
  }
}

// =====================================================================
// CSR reduce over nodes (STREAMING): h = x + sum(msg[j]); fused stats. (x fp32)
// =====================================================================
__global__ __launch_bounds__(256) void k_red_n(
    const unsigned short* __restrict__ msg, const float* x_in, float* out,
    const int* __restrict__ ptr, const int* __restrict__ nbatch,
    float* __restrict__ gs1, float* __restrict__ gs2, int nN)
{
  __shared__ float ls1[NG], ls2[NG];
  if (threadIdx.x < NG) { ls1[threadIdx.x] = 0.f; ls2[threadIdx.x] = 0.f; }
  __syncthreads();
  int lane = threadIdx.x & 63;
  int wv = (int)((blockIdx.x * 256u + threadIdx.x) >> 6);
  int nw = (int)((gridDim.x * 256u) >> 6);
  for (int n = wv; n < nN; n += nw) {
    int p0 = ptr[n], p1 = ptr[n + 1];
    float s0 = 0.f, s1v = 0.f;
    for (int j = p0; j < p1; ++j) {
      unsigned u = *(const unsigned*)(msg + (size_t)j * 128 + lane * 2);
      s0 += bf2f((unsigned short)(u & 0xffffu));
      s1v += bf2f((unsigned short)(u >> 16));
    }
    size_t off = (size_t)n * 128 + lane * 2;
    float h0 = x_in[off] + s0, h1 = x_in[off + 1] + s1v;
    out[off] = h0; out[off + 1] = h1;
    float s = h0 + h1, ss = h0 * h0 + h1 * h1;
#pragma unroll
    for (int m = 1; m < 64; m <<= 1) { s += __shfl_xor(s, m); ss += __shfl_xor(ss, m); }
    if (lane == 0) { int g = nbatch[n]; atomicAdd(&ls1[g], s); atomicAdd(&ls2[g], ss); }
  }
  __syncthreads();
  if (threadIdx.x < NG) {
    atomicAdd(&gs1[threadIdx.x], ls1[threadIdx.x]);
    atomicAdd(&gs2[threadIdx.x], ls2[threadIdx.x]);
  }
}

// ---- affine table construction ----
__global__ __launch_bounds__(256) void k_mkaff(
    const float* __restrict__ s1, const float* __restrict__ s2,
    const float* __restrict__ cnt, int F,
    const float* __restrict__ w, const float* __restrict__ b,
    float* __restrict__ A, float* __restrict__ B)
{
  int idx = blockIdx.x * 256 + threadIdx.x;
  if (idx >= NG * F) return;
  int g = idx / F, f = idx - g * F;
  float norm = fmaxf(cnt[g], 1.f) * (float)F;
  float m = s1[g] / norm;
  float var = s2[g] / norm - m * m;
  float inv = rsqrtf(var + EPS);
  float a = inv * w[f];
  A[idx] = a;
  B[idx] = b[f] - m * a;
}

__global__ __launch_bounds__(256) void k_idaff(float* __restrict__ A, float* __restrict__ B, int n)
{
  int idx = blockIdx.x * 256 + threadIdx.x;
  if (idx < n) { A[idx] = 1.f; B[idx] = 0.f; }
}

// ---- apply norm to x (in-place, fp32) ----
__global__ __launch_bounds__(256) void k_apply(
    float* h, const int* __restrict__ batch,
    const float* __restrict__ A, const float* __restrict__ B, int nN)
{
  int total = nN * 16;
  int stride = gridDim.x * 256;
  for (int idx = blockIdx.x * 256 + threadIdx.x; idx < total; idx += stride) {
    int row = idx >> 4, q = (idx & 15) * 8;
    int g = batch[row];
    float* hp = h + (size_t)row * 128 + q;
    float4 f0 = *(const float4*)hp;
    float4 f1 = *(const float4*)(hp + 4);
    float vv[8] = {f0.x,f0.y,f0.z,f0.w,f1.x,f1.y,f1.z,f1.w};
#pragma unroll
    for (int k = 0; k < 8; ++k) vv[k] = vv[k] * A[(g << 7) + q + k] + B[(g << 7) + q + k];
    float4 g0 = {vv[0],vv[1],vv[2],vv[3]}, g1 = {vv[4],vv[5],vv[6],vv[7]};
    *(float4*)hp = g0;
    *(float4*)(hp + 4) = g1;
  }
}

__global__ __launch_bounds__(256) void k_count(
    const int* __restrict__ batch, int n, float* __restrict__ cnt)
{
  __shared__ float lc[NG];
  if (threadIdx.x < NG) lc[threadIdx.x] = 0.f;
  __syncthreads();
  for (int i = blockIdx.x * 256 + threadIdx.x; i < n; i += gridDim.x * 256)
    atomicAdd(&lc[batch[i]], 1.f);
  __syncthreads();
  if (threadIdx.x < NG) atomicAdd(&cnt[threadIdx.x], lc[threadIdx.x]);
}

// ---- CSR build ----
__global__ __launch_bounds__(256) void k_hist(
    const int* __restrict__ dst, int n, int* __restrict__ cnt)
{
  for (int i = blockIdx.x * 256 + threadIdx.x; i < n; i += gridDim.x * 256)
    atomicAdd(&cnt[dst[i]], 1);
}

__global__ __launch_bounds__(256) void k_scan1(
    const int* __restrict__ in, int* __restrict__ out, int* __restrict__ bsum, int n)
{
  __shared__ int wtot[4];
  int tid = threadIdx.x, lane = tid & 63, wid = tid >> 6;
  int base = blockIdx.x * 1024 + tid * 4;
  int v[4];
#pragma unroll
  for (int k = 0; k < 4; ++k) v[k] = (base + k < n) ? in[base + k] : 0;
  int tsum = v[0] + v[1] + v[2] + v[3];
  int incl = tsum;
#pragma unroll
  for (int off = 1; off < 64; off <<= 1) {
    int up = __shfl_up(incl, off);
    if (lane >= off) incl += up;
  }
  if (lane == 63) wtot[wid] = incl;
  __syncthreads();
  if (tid == 0) {
    int r = 0;
#pragma unroll
    for (int w2 = 0; w2 < 4; ++w2) { int t = wtot[w2]; wtot[w2] = r; r += t; }
    bsum[blockIdx.x] = r;
  }
  __syncthreads();
  int excl = wtot[wid] + incl - tsum;
#pragma unroll
  for (int k = 0; k < 4; ++k) {
    if (base + k < n) out[base + k] = excl;
    excl += v[k];
  }
}

__global__ __launch_bounds__(256) void k_scan2(int* __restrict__ bsum, int nb, int* __restrict__ total_out)
{
  __shared__ int wtot[4];
  int tid = threadIdx.x, lane = tid & 63, wid = tid >> 6;
  int base = tid * 4;
  int v[4];
#pragma unroll
  for (int k = 0; k < 4; ++k) v[k] = (base + k < nb) ? bsum[base + k] : 0;
  int tsum = v[0] + v[1] + v[2] + v[3];
  int incl = tsum;
#pragma unroll
  for (int off = 1; off < 64; off <<= 1) {
    int up = __shfl_up(incl, off);
    if (lane >= off) incl += up;
  }
  if (lane == 63) wtot[wid] = incl;
  __syncthreads();
  if (tid == 0) {
    int r = 0;
#pragma unroll
    for (int w2 = 0; w2 < 4; ++w2) { int t = wtot[w2]; wtot[w2] = r; r += t; }
    *total_out = r;
  }
  __syncthreads();
  int excl = wtot[wid] + incl - tsum;
#pragma unroll
  for (int k = 0; k < 4; ++k) {
    if (base + k < nb) bsum[base + k] = excl;
    excl += v[k];
  }
}

__global__ __launch_bounds__(256) void k_scan3(
    int* __restrict__ ptr, int* __restrict__ cur, const int* __restrict__ bsum, int n)
{
  for (int i = blockIdx.x * 256 + threadIdx.x; i < n; i += gridDim.x * 256) {
    int v = ptr[i] + bsum[i >> 10];
    ptr[i] = v; cur[i] = v;
  }
}

__global__ __launch_bounds__(256) void k_scatter(
    const int* __restrict__ dst, int* __restrict__ cur, int* __restrict__ perm, int n)
{
  for (int i = blockIdx.x * 256 + threadIdx.x; i < n; i += gridDim.x * 256) {
    int d = dst[i];
    int p = atomicAdd(&cur[d], 1);
    perm[p] = i;
  }
}

// ---- inverse permutation: opos[perm[j]] = j ----
__global__ __launch_bounds__(256) void k_invperm(
    const int* __restrict__ perm, int* __restrict__ opos, int n)
{
  for (int j = blockIdx.x * 256 + threadIdx.x; j < n; j += gridDim.x * 256)
    opos[perm[j]] = j;
}

// ---- weight prep ----
__global__ __launch_bounds__(256) void k_wt(
    const float* __restrict__ W, unsigned short* __restrict__ Wt, int K, int NO)
{
  int idx = blockIdx.x * 256 + threadIdx.x;
  if (idx >= K * NO) return;
  int k = idx / NO, j = idx - k * NO;
  Wt[(size_t)j * K + k] = f2bf(W[idx]);
}

extern "C" void kernel_launch(void* const* d_in, const int* in_sizes, int n_in,
                              void* d_out, int out_size, void* d_ws, size_t ws_size,
                              hipStream_t stream)
{
  const float* x0    = (const float*)d_in[0];
  const float* e0    = (const float*)d_in[1];
  const float* a0    = (const float*)d_in[2];
  const float* W_ne  = (const float*)d_in[3];
  const float* b_ne  = (const float*)d_in[4];
  const float* g_e   = (const float*)d_in[5];
  const float* be_e  = (const float*)d_in[6];
  const float* W_ea  = (const float*)d_in[7];
  const float* b_ea  = (const float*)d_in[8];
  const float* g_a   = (const float*)d_in[9];
  const float* be_a  = (const float*)d_in[10];
  const float* W_emp = (const float*)d_in[11];
  const float* b_emp = (const float*)d_in[12];
  const float* g_emp = (const float*)d_in[13];
  const float* be_emp= (const float*)d_in[14];
  const float* W_nmp = (const float*)d_in[15];
  const float* b_nmp = (const float*)d_in[16];
  const float* g_nmp = (const float*)d_in[17];
  const float* be_nmp= (const float*)d_in[18];
  const int* node_batch  = (const int*)d_in[19];
  const int* edge_index  = (const int*)d_in[20];
  const int* edge_batch  = (const int*)d_in[21];
  const int* tb_index    = (const int*)d_in[22];
  const int* angle_batch = (const int*)d_in[23];

  const int N = in_sizes[0] / 128;
  const int E = in_sizes[1] / 64;
  const int A = in_sizes[2] / 64;

  // ---- workspace layout (bytes, 256-aligned) ----
  char* wsp = (char*)d_ws;
  auto alloc = [&](size_t bytes) { char* p = wsp; wsp += (bytes + 255) & ~(size_t)255; return p; };
  unsigned short* eAB  = (unsigned short*)alloc((size_t)E * 64 * 2);   // e intermediate (bf16)
  unsigned short* aAB  = (unsigned short*)alloc((size_t)A * 64 * 2);   // a intermediate (bf16)
  unsigned short* msg  = (unsigned short*)alloc((size_t)A * 64 * 2);   // msg_e / msg_n (CSR-ordered)
  unsigned short* P    = (unsigned short*)alloc((size_t)N * 384 * 2);  // x partials (lives to stage 4)
  unsigned short* PAE  = (unsigned short*)alloc((size_t)E * 256 * 2);  // angle+emp partials (de-interleaved)
  int* ptr_n  = (int*)alloc((size_t)(N + 1) * 4);
  int* cur_n  = (int*)alloc((size_t)N * 4);
  int* perm_n = (int*)alloc((size_t)E * 4);
  int* ptr_e  = (int*)alloc((size_t)(E + 1) * 4);
  int* cur_e  = (int*)alloc((size_t)E * 4);
  int* perm_e = (int*)alloc((size_t)A * 4);
  int* opos_n = (int*)alloc((size_t)E * 4);   // edge  -> CSR slot (node reduce)
  int* opos_e = (int*)alloc((size_t)A * 4);   // angle -> CSR slot (edge reduce)
  int* bsum   = (int*)alloc(4096 * 4);
  float* stats = (float*)alloc(5 * NG * 4);   // contiguous: s1,s2,cnt_n,cnt_e,cnt_a
  float* s1    = stats;
  float* s2    = stats + NG;
  float* cnt_n = stats + 2 * NG;
  float* cnt_e = stats + 3 * NG;
  float* cnt_a = stats + 4 * NG;
  float* afE_idA = (float*)alloc(1024 * 4); float* afE_idB = (float*)alloc(1024 * 4);
  float* afA_idA = (float*)alloc(1024 * 4); float* afA_idB = (float*)alloc(1024 * 4);
  float* afE1A   = (float*)alloc(1024 * 4); float* afE1B   = (float*)alloc(1024 * 4);
  float* afE2A   = (float*)alloc(1024 * 4); float* afE2B   = (float*)alloc(1024 * 4);
  float* afA1A   = (float*)alloc(1024 * 4); float* afA1B   = (float*)alloc(1024 * 4);
  float* afXA    = (float*)alloc(2048 * 4); float* afXB    = (float*)alloc(2048 * 4);
  unsigned short* wt_ne  = (unsigned short*)alloc((size_t)2 * 320 * 64 * 2);
  unsigned short* wt_ea  = (unsigned short*)alloc((size_t)2 * 192 * 64 * 2);
  unsigned short* wt_emp = (unsigned short*)alloc((size_t)2 * 192 * 64 * 2);
  unsigned short* wt_nmp = (unsigned short*)alloc((size_t)2 * 320 * 128 * 2);

  float* x_out = (float*)d_out;

  // ---- one-time prep ----
  for (int i = 0; i < 2; ++i) {
    k_wt<<<(320*64 + 255)/256, 256, 0, stream>>>(W_ne  + (size_t)i*320*64,  wt_ne  + (size_t)i*320*64,  320, 64);
    k_wt<<<(192*64 + 255)/256, 256, 0, stream>>>(W_ea  + (size_t)i*192*64,  wt_ea  + (size_t)i*192*64,  192, 64);
    k_wt<<<(192*64 + 255)/256, 256, 0, stream>>>(W_emp + (size_t)i*192*64,  wt_emp + (size_t)i*192*64,  192, 64);
    k_wt<<<(320*128 + 255)/256, 256, 0, stream>>>(W_nmp + (size_t)i*320*128, wt_nmp + (size_t)i*320*128, 320, 128);
  }
  hipMemsetAsync(stats, 0, 5 * NG * 4, stream);
  k_count<<<512, 256, 0, stream>>>(node_batch, N, cnt_n);
  k_count<<<512, 256, 0, stream>>>(edge_batch, E, cnt_e);
  k_count<<<512, 256, 0, stream>>>(angle_batch, A, cnt_a);
  k_idaff<<<4, 256, 0, stream>>>(afE_idA, afE_idB, 1024);
  k_idaff<<<4, 256, 0, stream>>>(afA_idA, afA_idB, 1024);

  // CSR over nodes (dst of edge_index) and edges (dst of threebody) + inverse perms
  hipMemsetAsync(cur_n, 0, (size_t)N * 4, stream);
  hipMemsetAsync(cur_e, 0, (size_t)E * 4, stream);
  k_hist<<<1024, 256, 0, stream>>>(edge_index + E, E, cur_n);
  k_hist<<<1024, 256, 0, stream>>>(tb_index + A, A, cur_e);
  int nbN = (N + 1023) / 1024, nbE = (E + 1023) / 1024;
  k_scan1<<<nbN, 256, 0, stream>>>(cur_n, ptr_n, bsum, N);
  k_scan2<<<1, 256, 0, stream>>>(bsum, nbN, ptr_n + N);
  k_scan3<<<1024, 256, 0, stream>>>(ptr_n, cur_n, bsum, N);
  k_scatter<<<1024, 256, 0, stream>>>(edge_index + E, cur_n, perm_n, E);
  k_invperm<<<1024, 256, 0, stream>>>(perm_n, opos_n, E);
  k_scan1<<<nbE, 256, 0, stream>>>(cur_e, ptr_e, bsum, E);
  k_scan2<<<1, 256, 0, stream>>>(bsum, nbE, ptr_e + E);
  k_scan3<<<1024, 256, 0, stream>>>(ptr_e, cur_e, bsum, E);
  k_scatter<<<1024, 256, 0, stream>>>(tb_index + A, cur_e, perm_e, A);
  k_invperm<<<1024, 256, 0, stream>>>(perm_e, opos_e, A);

  const float* x_cur = x0;
  int blkE = (E / 16 + 3) / 4;
  int blkA = (A / 16 + 3) / 4;
  int blkN = (N / 16 + 3) / 4;

  for (int i = 0; i < 2; ++i) {
    const float* fEinA = (i == 0) ? afE_idA : afE2A;
    const float* fEinB = (i == 0) ? afE_idB : afE2B;
    const float* fAinA = (i == 0) ? afA_idA : afA1A;
    const float* fAinB = (i == 0) ? afA_idB : afA1B;

    // 0. dense x-partials (P persists through stage 4)
    k_dense_x<<<blkN, 256, 0, stream>>>(x_cur, wt_ne + (size_t)i*320*64,
                                        wt_nmp + (size_t)i*320*128, P, N);

    // 1. edge stage -> affE1
    hipMemsetAsync(s1, 0, 2 * NG * 4, stream);
    if (i == 0)
      k_edge<true><<<blkE, 256, 0, stream>>>(P, (const void*)e0, eAB, edge_index, edge_batch,
                                             wt_ne + (size_t)i*320*64, b_ne + i*64,
                                             fEinA, fEinB, s1, s2, E);
    else
      k_edge<false><<<blkE, 256, 0, stream>>>(P, (const void*)eAB, eAB, edge_index, edge_batch,
                                              wt_ne + (size_t)i*320*64, b_ne + i*64,
                                              fEinA, fEinB, s1, s2, E);
    k_mkaff<<<4, 256, 0, stream>>>(s1, s2, cnt_e, 64, g_e + i*64, be_e + i*64, afE1A, afE1B);

    // 1.5 dense angle+emp partials -> PAE (de-interleaved)
    k_prep_e<<<blkE, 256, 0, stream>>>(eAB, edge_batch, afE1A, afE1B,
                                       wt_ea + (size_t)i*192*64, wt_emp + (size_t)i*192*64,
                                       PAE, E);

    // 2. angle stage (PA gathers only) -> affA1
    hipMemsetAsync(s1, 0, 2 * NG * 4, stream);
    if (i == 0)
      k_angle<true><<<blkA, 256, 0, stream>>>(PAE, (const void*)a0, aAB, tb_index, angle_batch,
                                              wt_ea + (size_t)i*192*64, b_ea + i*64,
                                              fAinA, fAinB, s1, s2, A);
    else
      k_angle<false><<<blkA, 256, 0, stream>>>(PAE, (const void*)aAB, aAB, tb_index, angle_batch,
                                               wt_ea + (size_t)i*192*64, b_ea + i*64,
                                               fAinA, fAinB, s1, s2, A);
    k_mkaff<<<4, 256, 0, stream>>>(s1, s2, cnt_a, 64, g_a + i*64, be_a + i*64, afA1A, afA1B);

    // 3. emp finish -> msg (CSR order); STREAMING reduce -> affE2
    k_fin_emp<<<blkA, 256, 0, stream>>>(PAE, aAB, tb_index, angle_batch, opos_e,
                                        wt_emp + (size_t)i*192*64, b_emp + i*64,
                                        afA1A, afA1B, msg, A);
    hipMemsetAsync(s1, 0, 2 * NG * 4, stream);
    k_red_e<<<2048, 256, 0, stream>>>(msg, eAB, eAB, ptr_e, edge_batch,
                                      afE1A, afE1B, s1, s2, E);
    k_mkaff<<<4, 256, 0, stream>>>(s1, s2, cnt_e, 64, g_emp + i*64, be_emp + i*64, afE2A, afE2B);

    // 4. nmp finish -> msg (CSR order); STREAMING reduce; apply
    k_fin_nmp<<<blkE, 256, 0, stream>>>(P, eAB, edge_index, edge_batch, opos_n,
                                        wt_nmp + (size_t)i*320*128, b_nmp + i*128,
                                        afE2A, afE2B, msg, E);
    hipMemsetAsync(s1, 0, 2 * NG * 4, stream);
    k_red_n<<<2048, 256, 0, stream>>>(msg, x_cur, x_out, ptr_n, node_batch,
                                      s1, s2, N);
    k_mkaff<<<8, 256, 0, stream>>>(s1, s2, cnt_n, 128, g_nmp + i*128, be_nmp + i*128, afXA, afXB);
    k_apply<<<2048, 256, 0, stream>>>(x_out, node_batch, afXA, afXB, N);

    x_cur = x_out;
  }
}

// Round 14
// 1550.760 us; speedup vs baseline: 1.0499x; 1.0218x over previous
//
#include <hip/hip_runtime.h>

typedef __attribute__((ext_vector_type(8))) short bf16x8_t;
typedef __attribute__((ext_vector_type(4))) short bf16x4_t;
typedef __attribute__((ext_vector_type(4))) float f32x4_t;

constexpr int NG = 16;
constexpr float EPS = 1e-5f;

__device__ inline unsigned short f2bf(float f) {
  unsigned u = __builtin_bit_cast(unsigned, f);
  u += 0x7FFFu + ((u >> 16) & 1u);
  return (unsigned short)(u >> 16);
}
__device__ inline float bf2f(unsigned short u) {
  unsigned x = ((unsigned)u) << 16;
  return __builtin_bit_cast(float, x);
}

// Build the per-(graph,feature) affine table in LDS from raw stats.
// gamma==nullptr -> identity. Call + __syncthreads() before use.
__device__ inline void mkaff_lds(float* lA, float* lB,
    const float* s1, const float* s2, const float* cnt,
    const float* gamma, const float* beta, int F, int tid) {
  int total = NG * F;
  for (int i = tid; i < total; i += 256) {
    float a = 1.f, b = 0.f;
    if (gamma != nullptr) {
      int g = i / F, f = i - g * F;
      float norm = fmaxf(cnt[g], 1.f) * (float)F;
      float m = s1[g] / norm;
      float var = s2[g] / norm - m * m;
      float inv = rsqrtf(var + EPS);
      a = inv * gamma[f];
      b = beta[f] - m * a;
    }
    lA[i] = a; lB[i] = b;
  }
}

// load 8 contiguous elements as f32 from fp32 or bf16 storage
template<bool F32>
__device__ inline void ldrow8(const void* base, size_t off, float v[8]) {
  if constexpr (F32) {
    const float* p = (const float*)base + off;
    float4 f0 = *(const float4*)p, f1 = *(const float4*)(p + 4);
    v[0]=f0.x; v[1]=f0.y; v[2]=f0.z; v[3]=f0.w;
    v[4]=f1.x; v[5]=f1.y; v[6]=f1.z; v[7]=f1.w;
  } else {
    bf16x8_t t = *(const bf16x8_t*)((const unsigned short*)base + off);
#pragma unroll
    for (int k = 0; k < 8; ++k) v[k] = bf2f((unsigned short)t[k]);
  }
}

// =====================================================================
// Dense partial GEMM over nodes (coalesced):
//   P[n] = x̂[n] @ [Wne_s | Wne_d | Wnmp_s | Wnmp_d]  (N x 384 bf16, swizzled)
// APX: apply pending node affine (layer-1; x holds raw h from layer-0 red_n)
// =====================================================================
template<bool APX>
__global__ __launch_bounds__(256) void k_dense_x(
    const float* __restrict__ x, const int* __restrict__ nbatch,
    const float* __restrict__ s1, const float* __restrict__ s2,
    const float* __restrict__ cnt,
    const float* __restrict__ gm, const float* __restrict__ bt,
    const unsigned short* __restrict__ WtNE,   // [64][320]
    const unsigned short* __restrict__ WtNM,   // [128][320]
    unsigned short* __restrict__ P, int nN)
{
  __shared__ float lA[APX ? 2048 : 1], lB[APX ? 2048 : 1];
  if (APX) {
    mkaff_lds(lA, lB, s1, s2, cnt, gm, bt, 128, threadIdx.x);
    __syncthreads();
  }
  int gw = (int)((blockIdx.x * 256u + threadIdx.x) >> 6);
  int ntile = nN >> 4;
  if (gw >= ntile) return;
  int lane = threadIdx.x & 63;
  int colb = lane & 15;
  int ko = (lane >> 4) << 3;
  int rowb = (lane >> 4) << 2;
  int row = (gw << 4) + colb;
  int gx = APX ? nbatch[row] : 0;
  const float* xr = x + (size_t)row * 128;
  f32x4_t a1[4] = {}, a2[4] = {}, a3[8] = {}, a4[8] = {};
#pragma unroll
  for (int c = 0; c < 4; ++c) {
    float4 f0 = *(const float4*)(xr + c * 32 + ko);
    float4 f1 = *(const float4*)(xr + c * 32 + ko + 4);
    float vv[8] = {f0.x,f0.y,f0.z,f0.w,f1.x,f1.y,f1.z,f1.w};
    bf16x8_t a;
#pragma unroll
    for (int k = 0; k < 8; ++k) {
      float v = vv[k];
      if (APX) v = v * lA[(gx << 7) + c * 32 + ko + k] + lB[(gx << 7) + c * 32 + ko + k];
      a[k] = (short)f2bf(v);
    }
#pragma unroll
    for (int nb = 0; nb < 4; ++nb) {
      bf16x8_t b1 = *(const bf16x8_t*)(WtNE + (size_t)(nb * 16 + colb) * 320 + c * 32 + ko);
      a1[nb] = __builtin_amdgcn_mfma_f32_16x16x32_bf16(a, b1, a1[nb], 0, 0, 0);
      bf16x8_t b2 = *(const bf16x8_t*)(WtNE + (size_t)(nb * 16 + colb) * 320 + (c + 4) * 32 + ko);
      a2[nb] = __builtin_amdgcn_mfma_f32_16x16x32_bf16(a, b2, a2[nb], 0, 0, 0);
    }
#pragma unroll
    for (int nb = 0; nb < 8; ++nb) {
      bf16x8_t b3 = *(const bf16x8_t*)(WtNM + (size_t)(nb * 16 + colb) * 320 + c * 32 + ko);
      a3[nb] = __builtin_amdgcn_mfma_f32_16x16x32_bf16(a, b3, a3[nb], 0, 0, 0);
      bf16x8_t b4 = *(const bf16x8_t*)(WtNM + (size_t)(nb * 16 + colb) * 320 + (c + 4) * 32 + ko);
      a4[nb] = __builtin_amdgcn_mfma_f32_16x16x32_bf16(a, b4, a4[nb], 0, 0, 0);
    }
  }
#pragma unroll
  for (int r = 0; r < 4; ++r) {
    size_t ro = (size_t)((gw << 4) + rowb + r) * 384;
    bf16x4_t t1, t2;
#pragma unroll
    for (int nb = 0; nb < 4; ++nb) { t1[nb] = (short)f2bf(a1[nb][r]); t2[nb] = (short)f2bf(a2[nb][r]); }
    *(bf16x4_t*)(P + ro + colb * 4) = t1;
    *(bf16x4_t*)(P + ro + 64 + colb * 4) = t2;
    bf16x8_t t3, t4;
#pragma unroll
    for (int nb = 0; nb < 8; ++nb) { t3[nb] = (short)f2bf(a3[nb][r]); t4[nb] = (short)f2bf(a4[nb][r]); }
    *(bf16x8_t*)(P + ro + 128 + colb * 8) = t3;
    *(bf16x8_t*)(P + ro + 256 + colb * 8) = t4;
  }
}

// =====================================================================
// Dense angle+emp partials over edges (coalesced, one eAB read):
//   ê = affE1(e);  PA1=ê@Wea_s, PA2=ê@Wea_d, PE3=ê@Wemp_s, PE4=ê@Wemp_d
// PAE row (256 shorts), de-interleaved 128B blocks:
//   [0..63]=PA1, [64..127]=PE3, [128..191]=PA2, [192..255]=PE4
// Affine built in-kernel from edge-update stats.
// =====================================================================
__global__ __launch_bounds__(256) void k_prep_e(
    const unsigned short* __restrict__ eA, const int* __restrict__ ebatch,
    const float* __restrict__ s1, const float* __restrict__ s2,
    const float* __restrict__ cnt,
    const float* __restrict__ gm, const float* __restrict__ bt,
    const unsigned short* __restrict__ WtA,    // wt_ea  [64][192]
    const unsigned short* __restrict__ WtP,    // wt_emp [64][192]
    unsigned short* __restrict__ PAE, int nE)
{
  __shared__ float lA[1024], lB[1024];
  mkaff_lds(lA, lB, s1, s2, cnt, gm, bt, 64, threadIdx.x);
  __syncthreads();
  int gw = (int)((blockIdx.x * 256u + threadIdx.x) >> 6);
  int ntile = nE >> 4;
  if (gw >= ntile) return;
  int lane = threadIdx.x & 63;
  int colb = lane & 15;
  int ko = (lane >> 4) << 3;
  int rowb = (lane >> 4) << 2;
  int row = (gw << 4) + colb;
  int ge = ebatch[row];
  f32x4_t pa1[4] = {}, pa2[4] = {}, pe3[4] = {}, pe4[4] = {};
#pragma unroll
  for (int c2 = 0; c2 < 2; ++c2) {
    int fb = c2 * 32 + ko;
    bf16x8_t t = *(const bf16x8_t*)(eA + (size_t)row * 64 + fb);
    bf16x8_t an;
#pragma unroll
    for (int k = 0; k < 8; ++k)
      an[k] = (short)f2bf(bf2f((unsigned short)t[k]) * lA[ge*64 + fb + k] + lB[ge*64 + fb + k]);
#pragma unroll
    for (int nb = 0; nb < 4; ++nb) {
      size_t wb = (size_t)(nb * 16 + colb) * 192;
      bf16x8_t b;
      b = *(const bf16x8_t*)(WtA + wb + c2 * 32 + ko);
      pa1[nb] = __builtin_amdgcn_mfma_f32_16x16x32_bf16(an, b, pa1[nb], 0, 0, 0);
      b = *(const bf16x8_t*)(WtA + wb + 64 + c2 * 32 + ko);
      pa2[nb] = __builtin_amdgcn_mfma_f32_16x16x32_bf16(an, b, pa2[nb], 0, 0, 0);
      b = *(const bf16x8_t*)(WtP + wb + c2 * 32 + ko);
      pe3[nb] = __builtin_amdgcn_mfma_f32_16x16x32_bf16(an, b, pe3[nb], 0, 0, 0);
      b = *(const bf16x8_t*)(WtP + wb + 64 + c2 * 32 + ko);
      pe4[nb] = __builtin_amdgcn_mfma_f32_16x16x32_bf16(an, b, pe4[nb], 0, 0, 0);
    }
  }
#pragma unroll
  for (int r = 0; r < 4; ++r) {
    size_t ro = (size_t)((gw << 4) + rowb + r) * 256;
    bf16x4_t t1, t3, t2, t4;
#pragma unroll
    for (int nb = 0; nb < 4; ++nb) {
      t1[nb] = (short)f2bf(pa1[nb][r]); t3[nb] = (short)f2bf(pe3[nb][r]);
      t2[nb] = (short)f2bf(pa2[nb][r]); t4[nb] = (short)f2bf(pe4[nb][r]);
    }
    *(bf16x4_t*)(PAE + ro + colb * 4) = t1;          // PA1
    *(bf16x4_t*)(PAE + ro + 64 + colb * 4) = t3;     // PE3
    *(bf16x4_t*)(PAE + ro + 128 + colb * 4) = t2;    // PA2
    *(bf16x4_t*)(PAE + ro + 192 + colb * 4) = t4;    // PE4
  }
}

// =====================================================================
// EDGE stage: e_out(bf16) = ê + P_T1[s]+P_T2[d] + ê@Wne_e + b  (+stats)
// Input affine built in-kernel (identity on layer 0: gm==nullptr).
// =====================================================================
template<bool EF32>
__global__ __launch_bounds__(256) void k_edge(
    const unsigned short* __restrict__ P, const void* e_in, unsigned short* e_out,
    const int* __restrict__ ei, const int* __restrict__ ebatch,
    const float* __restrict__ is1, const float* __restrict__ is2,
    const float* __restrict__ icnt,
    const float* __restrict__ igm, const float* __restrict__ ibt,
    const unsigned short* __restrict__ Wt,    // wt_ne [64][320]
    const float* __restrict__ bias,
    float* __restrict__ gs1, float* __restrict__ gs2, int nE)
{
  __shared__ float lA[1024], lB[1024];
  __shared__ float ls1[NG], ls2[NG];
  __shared__ __align__(16) unsigned short tl[4][16][72];
  mkaff_lds(lA, lB, is1, is2, icnt, igm, ibt, 64, threadIdx.x);
  if (threadIdx.x < NG) { ls1[threadIdx.x] = 0.f; ls2[threadIdx.x] = 0.f; }
  __syncthreads();
  int gw = (int)((blockIdx.x * 256u + threadIdx.x) >> 6);
  int ntile = nE >> 4;
  bool act = gw < ntile;
  int lane = threadIdx.x & 63;
  int wid = threadIdx.x >> 6;
  int colb = lane & 15;
  int ko = (lane >> 4) << 3;
  int rowb = (lane >> 4) << 2;
  float sr[4] = {0.f,0.f,0.f,0.f}, ssr[4] = {0.f,0.f,0.f,0.f};
  if (act) {
    int sI[4], dI[4];
#pragma unroll
    for (int r = 0; r < 4; ++r) {
      int e_r = (gw << 4) + rowb + r;
      sI[r] = ei[e_r]; dI[r] = ei[nE + e_r];
    }
    bf16x4_t g1[4], g2[4];
#pragma unroll
    for (int r = 0; r < 4; ++r) {
      g1[r] = *(const bf16x4_t*)(P + (size_t)sI[r] * 384 + colb * 4);
      g2[r] = *(const bf16x4_t*)(P + (size_t)dI[r] * 384 + 64 + colb * 4);
    }
    int row = (gw << 4) + colb;
    int ge = ebatch[row];
    f32x4_t acc[4] = {};
#pragma unroll
    for (int c2 = 0; c2 < 2; ++c2) {
      int fb = c2 * 32 + ko;
      float vv[8];
      ldrow8<EF32>(e_in, (size_t)row * 64 + fb, vv);
      bf16x8_t a;
#pragma unroll
      for (int k = 0; k < 8; ++k) a[k] = (short)f2bf(vv[k] * lA[ge*64 + fb + k] + lB[ge*64 + fb + k]);
      *(bf16x8_t*)&tl[wid][colb][fb] = a;
#pragma unroll
      for (int nb = 0; nb < 4; ++nb) {
        bf16x8_t b = *(const bf16x8_t*)(Wt + (size_t)(nb * 16 + colb) * 320 + (8 + c2) * 32 + ko);
        acc[nb] = __builtin_amdgcn_mfma_f32_16x16x32_bf16(a, b, acc[nb], 0, 0, 0);
      }
    }
#pragma unroll
    for (int r = 0; r < 4; ++r) {
      int e_ = (gw << 4) + rowb + r;
#pragma unroll
      for (int nb = 0; nb < 4; ++nb) {
        int col = nb * 16 + colb;
        size_t off = (size_t)e_ * 64 + col;
        float nv = bf2f(tl[wid][rowb + r][col]);
        float vv = nv + bias[col]
                 + acc[nb][r] + bf2f((unsigned short)g1[r][nb]) + bf2f((unsigned short)g2[r][nb]);
        e_out[off] = f2bf(vv);
        sr[r] += vv; ssr[r] += vv * vv;
      }
    }
  }
#pragma unroll
  for (int m = 1; m <= 8; m <<= 1)
#pragma unroll
    for (int r = 0; r < 4; ++r) { sr[r] += __shfl_xor(sr[r], m); ssr[r] += __shfl_xor(ssr[r], m); }
  if (act && colb == 0) {
#pragma unroll
    for (int r = 0; r < 4; ++r) {
      int g = ebatch[(gw << 4) + rowb + r];
      atomicAdd(&ls1[g], sr[r]); atomicAdd(&ls2[g], ssr[r]);
    }
  }
  __syncthreads();
  if (threadIdx.x < NG) {
    atomicAdd(&gs1[threadIdx.x], ls1[threadIdx.x]);
    atomicAdd(&gs2[threadIdx.x], ls2[threadIdx.x]);
  }
}

// =====================================================================
// ANGLE stage: gathers only PA1/PA2.
//   a_out(bf16) = â + PA1[s]+PA2[d] + â@Wea_a + b (+stats)
// Input affine in-kernel (identity layer 0).
// =====================================================================
template<bool AF32>
__global__ __launch_bounds__(256) void k_angle(
    const unsigned short* __restrict__ PAE,
    const void* a_in, unsigned short* a_out,
    const int* __restrict__ ti, const int* __restrict__ abatch,
    const float* __restrict__ is1, const float* __restrict__ is2,
    const float* __restrict__ icnt,
    const float* __restrict__ igm, const float* __restrict__ ibt,
    const unsigned short* __restrict__ Wt,    // wt_ea [64][192]
    const float* __restrict__ bias,
    float* __restrict__ gs1, float* __restrict__ gs2, int nA)
{
  __shared__ float lAA[1024], lAB[1024];
  __shared__ float ls1[NG], ls2[NG];
  __shared__ __align__(16) unsigned short tl[4][16][72];
  mkaff_lds(lAA, lAB, is1, is2, icnt, igm, ibt, 64, threadIdx.x);
  if (threadIdx.x < NG) { ls1[threadIdx.x] = 0.f; ls2[threadIdx.x] = 0.f; }
  __syncthreads();
  int gw = (int)((blockIdx.x * 256u + threadIdx.x) >> 6);
  int ntile = nA >> 4;
  bool act = gw < ntile;
  int lane = threadIdx.x & 63;
  int wid = threadIdx.x >> 6;
  int colb = lane & 15;
  int ko = (lane >> 4) << 3;
  int rowb = (lane >> 4) << 2;
  float sr[4] = {0.f,0.f,0.f,0.f}, ssr[4] = {0.f,0.f,0.f,0.f};
  if (act) {
    int sI[4], dI[4];
#pragma unroll
    for (int r = 0; r < 4; ++r) {
      int a_r = (gw << 4) + rowb + r;
      sI[r] = ti[a_r]; dI[r] = ti[nA + a_r];
    }
    bf16x4_t gS[4], gD[4];
#pragma unroll
    for (int r = 0; r < 4; ++r) {
      gS[r] = *(const bf16x4_t*)(PAE + (size_t)sI[r] * 256 + colb * 4);          // PA1
      gD[r] = *(const bf16x4_t*)(PAE + (size_t)dI[r] * 256 + 128 + colb * 4);    // PA2
    }
    int row = (gw << 4) + colb;
    int ga = abatch[row];
    f32x4_t acc[4] = {};
#pragma unroll
    for (int c2 = 0; c2 < 2; ++c2) {
      int fb = c2 * 32 + ko;
      float vv[8];
      ldrow8<AF32>(a_in, (size_t)row * 64 + fb, vv);
      bf16x8_t a;
#pragma unroll
      for (int k = 0; k < 8; ++k) a[k] = (short)f2bf(vv[k] * lAA[ga*64 + fb + k] + lAB[ga*64 + fb + k]);
      *(bf16x8_t*)&tl[wid][colb][fb] = a;
#pragma unroll
      for (int nb = 0; nb < 4; ++nb) {
        bf16x8_t b = *(const bf16x8_t*)(Wt + (size_t)(nb * 16 + colb) * 192 + 128 + c2 * 32 + ko);
        acc[nb] = __builtin_amdgcn_mfma_f32_16x16x32_bf16(a, b, acc[nb], 0, 0, 0);
      }
    }
#pragma unroll
    for (int r = 0; r < 4; ++r) {
      int a_ = (gw << 4) + rowb + r;
#pragma unroll
      for (int nb = 0; nb < 4; ++nb) {
        int col = nb * 16 + colb;
        size_t off = (size_t)a_ * 64 + col;
        float nv = bf2f(tl[wid][rowb + r][col]);
        float vv = nv + bias[col] + acc[nb][r]
                 + bf2f((unsigned short)gS[r][nb]) + bf2f((unsigned short)gD[r][nb]);
        a_out[off] = f2bf(vv);
        sr[r] += vv; ssr[r] += vv * vv;
      }
    }
  }
#pragma unroll
  for (int m = 1; m <= 8; m <<= 1)
#pragma unroll
    for (int r = 0; r < 4; ++r) { sr[r] += __shfl_xor(sr[r], m); ssr[r] += __shfl_xor(ssr[r], m); }
  if (act && colb == 0) {
#pragma unroll
    for (int r = 0; r < 4; ++r) {
      int g = abatch[(gw << 4) + rowb + r];
      atomicAdd(&ls1[g], sr[r]); atomicAdd(&ls2[g], ssr[r]);
    }
  }
  __syncthreads();
  if (threadIdx.x < NG) {
    atomicAdd(&gs1[threadIdx.x], ls1[threadIdx.x]);
    atomicAdd(&gs2[threadIdx.x], ls2[threadIdx.x]);
  }
}

// =====================================================================
// emp finish: gathers PE3[s]/PE4[d]; writes msg in CSR ORDER (opos).
//   msg[opos[a]] = relu(PE3[s]+PE4[d] + affA1(a1)@Wemp_a + b)
// =====================================================================
__global__ __launch_bounds__(256) void k_fin_emp(
    const unsigned short* __restrict__ PAE,
    const unsigned short* __restrict__ a_, const int* __restrict__ ti,
    const int* __restrict__ abatch, const int* __restrict__ opos,
    const float* __restrict__ is1, const float* __restrict__ is2,
    const float* __restrict__ icnt,
    const float* __restrict__ igm, const float* __restrict__ ibt,
    const unsigned short* __restrict__ Wt,    // wt_emp [64][192]
    const float* __restrict__ bias,
    unsigned short* __restrict__ msg, int nA)
{
  __shared__ float lAA[1024], lAB[1024];
  mkaff_lds(lAA, lAB, is1, is2, icnt, igm, ibt, 64, threadIdx.x);
  __syncthreads();
  int gw = (int)((blockIdx.x * 256u + threadIdx.x) >> 6);
  int ntile = nA >> 4;
  if (gw >= ntile) return;
  int lane = threadIdx.x & 63;
  int colb = lane & 15;
  int ko = (lane >> 4) << 3;
  int rowb = (lane >> 4) << 2;
  int sI[4], dI[4], wr[4];
#pragma unroll
  for (int r = 0; r < 4; ++r) {
    int a_r = (gw << 4) + rowb + r;
    sI[r] = ti[a_r]; dI[r] = ti[nA + a_r]; wr[r] = opos[a_r];
  }
  bf16x4_t g3[4], g4[4];
#pragma unroll
  for (int r = 0; r < 4; ++r) {
    g3[r] = *(const bf16x4_t*)(PAE + (size_t)sI[r] * 256 + 64 + colb * 4);     // PE3
    g4[r] = *(const bf16x4_t*)(PAE + (size_t)dI[r] * 256 + 192 + colb * 4);    // PE4
  }
  int row = (gw << 4) + colb;
  int ga = abatch[row];
  f32x4_t acc[4] = {};
#pragma unroll
  for (int c2 = 0; c2 < 2; ++c2) {
    int fb = c2 * 32 + ko;
    bf16x8_t t = *(const bf16x8_t*)(a_ + (size_t)row * 64 + fb);
    bf16x8_t a;
#pragma unroll
    for (int k = 0; k < 8; ++k)
      a[k] = (short)f2bf(bf2f((unsigned short)t[k]) * lAA[ga*64 + fb + k] + lAB[ga*64 + fb + k]);
#pragma unroll
    for (int nb = 0; nb < 4; ++nb) {
      bf16x8_t b = *(const bf16x8_t*)(Wt + (size_t)(nb * 16 + colb) * 192 + 128 + c2 * 32 + ko);
      acc[nb] = __builtin_amdgcn_mfma_f32_16x16x32_bf16(a, b, acc[nb], 0, 0, 0);
    }
  }
#pragma unroll
  for (int r = 0; r < 4; ++r) {
#pragma unroll
    for (int nb = 0; nb < 4; ++nb) {
      int col = nb * 16 + colb;
      float v = fmaxf(acc[nb][r] + bf2f((unsigned short)g3[r][nb]) + bf2f((unsigned short)g4[r][nb])
                      + bias[col], 0.f);
      msg[(size_t)wr[r] * 64 + col] = f2bf(v);
    }
  }
}

// =====================================================================
// nmp finish: gathers P T3/T4; writes msg in CSR ORDER (opos).
//   msg[opos[e]] = relu(P_T3[s]+P_T4[d] + affE2(e2)@Wnmp_e + b)
// =====================================================================
__global__ __launch_bounds__(256) void k_fin_nmp(
    const unsigned short* __restrict__ P,
    const unsigned short* __restrict__ e, const int* __restrict__ ei,
    const int* __restrict__ ebatch, const int* __restrict__ opos,
    const float* __restrict__ is1, const float* __restrict__ is2,
    const float* __restrict__ icnt,
    const float* __restrict__ igm, const float* __restrict__ ibt,
    const unsigned short* __restrict__ Wt,    // wt_nmp [128][320]
    const float* __restrict__ bias,
    unsigned short* __restrict__ msg, int nE)
{
  __shared__ float lEA[1024], lEB[1024];
  mkaff_lds(lEA, lEB, is1, is2, icnt, igm, ibt, 64, threadIdx.x);
  __syncthreads();
  int gw = (int)((blockIdx.x * 256u + threadIdx.x) >> 6);
  int ntile = nE >> 4;
  if (gw >= ntile) return;
  int lane = threadIdx.x & 63;
  int colb = lane & 15;
  int ko = (lane >> 4) << 3;
  int rowb = (lane >> 4) << 2;
  int sI[4], dI[4], wr[4];
#pragma unroll
  for (int r = 0; r < 4; ++r) {
    int e_r = (gw << 4) + rowb + r;
    sI[r] = ei[e_r]; dI[r] = ei[nE + e_r]; wr[r] = opos[e_r];
  }
  bf16x8_t g3[4], g4[4];
#pragma unroll
  for (int r = 0; r < 4; ++r) {
    g3[r] = *(const bf16x8_t*)(P + (size_t)sI[r] * 384 + 128 + colb * 8);
    g4[r] = *(const bf16x8_t*)(P + (size_t)dI[r] * 384 + 256 + colb * 8);
  }
  int row = (gw << 4) + colb;
  int ge = ebatch[row];
  f32x4_t acc[8] = {};
#pragma unroll
  for (int c2 = 0; c2 < 2; ++c2) {
    int fb = c2 * 32 + ko;
    bf16x8_t t = *(const bf16x8_t*)(e + (size_t)row * 64 + fb);
    bf16x8_t a;
#pragma unroll
    for (int k = 0; k < 8; ++k)
      a[k] = (short)f2bf(bf2f((unsigned short)t[k]) * lEA[ge*64 + fb + k] + lEB[ge*64 + fb + k]);
#pragma unroll
    for (int nb = 0; nb < 8; ++nb) {
      bf16x8_t b = *(const bf16x8_t*)(Wt + (size_t)(nb * 16 + colb) * 320 + (8 + c2) * 32 + ko);
      acc[nb] = __builtin_amdgcn_mfma_f32_16x16x32_bf16(a, b, acc[nb], 0, 0, 0);
    }
  }
#pragma unroll
  for (int r = 0; r < 4; ++r) {
#pragma unroll
    for (int nb = 0; nb < 8; ++nb) {
      int col = nb * 16 + colb;
      float v = fmaxf(acc[nb][r] + bf2f((unsigned short)g3[r][nb]) + bf2f((unsigned short)g4[r][nb])
                      + bias[col], 0.f);
      msg[(size_t)wr[r] * 128 + col] = f2bf(v);
    }
  }
}

// =====================================================================
// CSR reduce over edges (STREAMING): e2 = affE1(e1) + sum(msg[j]); +stats
// =====================================================================
__global__ __launch_bounds__(256) void k_red_e(
    const unsigned short* __restrict__ msg, const unsigned short* e_in, unsigned short* e_out,
    const int* __restrict__ ptr, const int* __restrict__ ebatch,
    const float* __restrict__ is1, const float* __restrict__ is2,
    const float* __restrict__ icnt,
    const float* __restrict__ igm, const float* __restrict__ ibt,
    float* __restrict__ gs1, float* __restrict__ gs2, int nE)
{
  __shared__ float lA[1024], lB[1024], ls1[NG], ls2[NG];
  mkaff_lds(lA, lB, is1, is2, icnt, igm, ibt, 64, threadIdx.x);
  if (threadIdx.x < NG) { ls1[threadIdx.x] = 0.f; ls2[threadIdx.x] = 0.f; }
  __syncthreads();
  int lane = threadIdx.x & 63;
  int wv = (int)((blockIdx.x * 256u + threadIdx.x) >> 6);
  int nw = (int)((gridDim.x * 256u) >> 6);
  for (int eidx = wv; eidx < nE; eidx += nw) {
    int p0 = ptr[eidx], p1 = ptr[eidx + 1];
    float sum = 0.f;
    for (int j = p0; j < p1; ++j)
      sum += bf2f(msg[(size_t)j * 64 + lane]);
    int g = ebatch[eidx];
    size_t off = (size_t)eidx * 64 + lane;
    float v = bf2f(e_in[off]) * lA[g*64 + lane] + lB[g*64 + lane] + sum;
    e_out[off] = f2bf(v);
    float s = v, ss = v * v;
#pragma unroll
    for (int m = 1; m < 64; m <<= 1) { s += __shfl_xor(s, m); ss += __shfl_xor(ss, m); }
    if (lane == 0) { atomicAdd(&ls1[g], s); atomicAdd(&ls2[g], ss); }
  }
  __syncthreads();
  if (threadIdx.x < NG) {
    atomicAdd(&gs1[threadIdx.x], ls1[threadIdx.x]);
    atomicAdd(&gs2[threadIdx.x], ls2[threadIdx.x]);
  }
}

// =====================================================================
// CSR reduce over nodes (STREAMING): h = x̂ + sum(msg[j]); +stats.
// APX: x holds raw layer-0 h; apply pending node affine on load.
// =====================================================================
template<bool APX>
__global__ __launch_bounds__(256) void k_red_n(
    const unsigned short* __restrict__ msg, const float* x_in, float* out,
    const int* __restrict__ ptr, const int* __restrict__ nbatch,
    const float* __restrict__ is1, const float* __restrict__ is2,
    const float* __restrict__ icnt,
    const float* __restrict__ igm, const float* __restrict__ ibt,
    float* __restrict__ gs1, float* __restrict__ gs2, int nN)
{
  __shared__ float lA[APX ? 2048 : 1], lB[APX ? 2048 : 1];
  __shared__ float ls1[NG], ls2[NG];
  if (APX) mkaff_lds(lA, lB, is1, is2, icnt, igm, ibt, 128, threadIdx.x);
  if (threadIdx.x < NG) { ls1[threadIdx.x] = 0.f; ls2[threadIdx.x] = 0.f; }
  __syncthreads();
  int lane = threadIdx.x & 63;
  int wv = (int)((blockIdx.x * 256u + threadIdx.x) >> 6);
  int nw = (int)((gridDim.x * 256u) >> 6);
  for (int n = wv; n < nN; n += nw) {
    int p0 = ptr[n], p1 = ptr[n + 1];
    float s0 = 0.f, s1v = 0.f;
    for (int j = p0; j < p1; ++j) {
      unsigned u = *(const unsigned*)(msg + (size_t)j * 128 + lane * 2);
      s0 += bf2f((unsigned short)(u & 0xffffu));
      s1v += bf2f((unsigned short)(u >> 16));
    }
    int g = nbatch[n];
    size_t off = (size_t)n * 128 + lane * 2;
    float x0v = x_in[off], x1v = x_in[off + 1];
    if (APX) {
      x0v = x0v * lA[(g << 7) + lane * 2] + lB[(g << 7) + lane * 2];
      x1v = x1v * lA[(g << 7) + lane * 2 + 1] + lB[(g << 7) + lane * 2 + 1];
    }
    float h0 = x0v + s0, h1 = x1v + s1v;
    out[off] = h0; out[off + 1] = h1;
    float s = h0 + h1, ss = h0 * h0 + h1 * h1;
#pragma unroll
    for (int m = 1; m < 64; m <<= 1) { s += __shfl_xor(s, m); ss += __shfl_xor(ss, m); }
    if (lane == 0) { atomicAdd(&ls1[g], s); atomicAdd(&ls2[g], ss); }
  }
  __syncthreads();
  if (threadIdx.x < NG) {
    atomicAdd(&gs1[threadIdx.x], ls1[threadIdx.x]);
    atomicAdd(&gs2[threadIdx.x], ls2[threadIdx.x]);
  }
}

// ---- final apply: h = affX(h) (in-place, fp32), table built in-kernel ----
__global__ __launch_bounds__(256) void k_apply(
    float* h, const int* __restrict__ batch,
    const float* __restrict__ is1, const float* __restrict__ is2,
    const float* __restrict__ icnt,
    const float* __restrict__ igm, const float* __restrict__ ibt, int nN)
{
  __shared__ float lA[2048], lB[2048];
  mkaff_lds(lA, lB, is1, is2, icnt, igm, ibt, 128, threadIdx.x);
  __syncthreads();
  int total = nN * 16;
  int stride = gridDim.x * 256;
  for (int idx = blockIdx.x * 256 + threadIdx.x; idx < total; idx += stride) {
    int row = idx >> 4, q = (idx & 15) * 8;
    int g = batch[row];
    float* hp = h + (size_t)row * 128 + q;
    float4 f0 = *(const float4*)hp;
    float4 f1 = *(const float4*)(hp + 4);
    float vv[8] = {f0.x,f0.y,f0.z,f0.w,f1.x,f1.y,f1.z,f1.w};
#pragma unroll
    for (int k = 0; k < 8; ++k) vv[k] = vv[k] * lA[(g << 7) + q + k] + lB[(g << 7) + q + k];
    float4 g0 = {vv[0],vv[1],vv[2],vv[3]}, g1 = {vv[4],vv[5],vv[6],vv[7]};
    *(float4*)hp = g0;
    *(float4*)(hp + 4) = g1;
  }
}

__global__ __launch_bounds__(256) void k_count(
    const int* __restrict__ batch, int n, float* __restrict__ cnt)
{
  __shared__ float lc[NG];
  if (threadIdx.x < NG) lc[threadIdx.x] = 0.f;
  __syncthreads();
  for (int i = blockIdx.x * 256 + threadIdx.x; i < n; i += gridDim.x * 256)
    atomicAdd(&lc[batch[i]], 1.f);
  __syncthreads();
  if (threadIdx.x < NG) atomicAdd(&cnt[threadIdx.x], lc[threadIdx.x]);
}

// ---- CSR build ----
__global__ __launch_bounds__(256) void k_hist(
    const int* __restrict__ dst, int n, int* __restrict__ cnt)
{
  for (int i = blockIdx.x * 256 + threadIdx.x; i < n; i += gridDim.x * 256)
    atomicAdd(&cnt[dst[i]], 1);
}

__global__ __launch_bounds__(256) void k_scan1(
    const int* __restrict__ in, int* __restrict__ out, int* __restrict__ bsum, int n)
{
  __shared__ int wtot[4];
  int tid = threadIdx.x, lane = tid & 63, wid = tid >> 6;
  int base = blockIdx.x * 1024 + tid * 4;
  int v[4];
#pragma unroll
  for (int k = 0; k < 4; ++k) v[k] = (base + k < n) ? in[base + k] : 0;
  int tsum = v[0] + v[1] + v[2] + v[3];
  int incl = tsum;
#pragma unroll
  for (int off = 1; off < 64; off <<= 1) {
    int up = __shfl_up(incl, off);
    if (lane >= off) incl += up;
  }
  if (lane == 63) wtot[wid] = incl;
  __syncthreads();
  if (tid == 0) {
    int r = 0;
#pragma unroll
    for (int w2 = 0; w2 < 4; ++w2) { int t = wtot[w2]; wtot[w2] = r; r += t; }
    bsum[blockIdx.x] = r;
  }
  __syncthreads();
  int excl = wtot[wid] + incl - tsum;
#pragma unroll
  for (int k = 0; k < 4; ++k) {
    if (base + k < n) out[base + k] = excl;
    excl += v[k];
  }
}

__global__ __launch_bounds__(256) void k_scan2(int* __restrict__ bsum, int nb, int* __restrict__ total_out)
{
  __shared__ int wtot[4];
  int tid = threadIdx.x, lane = tid & 63, wid = tid >> 6;
  int base = tid * 4;
  int v[4];
#pragma unroll
  for (int k = 0; k < 4; ++k) v[k] = (base + k < nb) ? bsum[base + k] : 0;
  int tsum = v[0] + v[1] + v[2] + v[3];
  int incl = tsum;
#pragma unroll
  for (int off = 1; off < 64; off <<= 1) {
    int up = __shfl_up(incl, off);
    if (lane >= off) incl += up;
  }
  if (lane == 63) wtot[wid] = incl;
  __syncthreads();
  if (tid == 0) {
    int r = 0;
#pragma unroll
    for (int w2 = 0; w2 < 4; ++w2) { int t = wtot[w2]; wtot[w2] = r; r += t; }
    *total_out = r;
  }
  __syncthreads();
  int excl = wtot[wid] + incl - tsum;
#pragma unroll
  for (int k = 0; k < 4; ++k) {
    if (base + k < nb) bsum[base + k] = excl;
    excl += v[k];
  }
}

__global__ __launch_bounds__(256) void k_scan3(
    int* __restrict__ ptr, int* __restrict__ cur, const int* __restrict__ bsum, int n)
{
  for (int i = blockIdx.x * 256 + threadIdx.x; i < n; i += gridDim.x * 256) {
    int v = ptr[i] + bsum[i >> 10];
    ptr[i] = v; cur[i] = v;
  }
}

__global__ __launch_bounds__(256) void k_scatter(
    const int* __restrict__ dst, int* __restrict__ cur, int* __restrict__ perm, int n)
{
  for (int i = blockIdx.x * 256 + threadIdx.x; i < n; i += gridDim.x * 256) {
    int d = dst[i];
    int p = atomicAdd(&cur[d], 1);
    perm[p] = i;
  }
}

// ---- inverse permutation: opos[perm[j]] = j ----
__global__ __launch_bounds__(256) void k_invperm(
    const int* __restrict__ perm, int* __restrict__ opos, int n)
{
  for (int j = blockIdx.x * 256 + threadIdx.x; j < n; j += gridDim.x * 256)
    opos[perm[j]] = j;
}

// ---- weight prep ----
__global__ __launch_bounds__(256) void k_wt(
    const float* __restrict__ W, unsigned short* __restrict__ Wt, int K, int NO)
{
  int idx = blockIdx.x * 256 + threadIdx.x;
  if (idx >= K * NO) return;
  int k = idx / NO, j = idx - k * NO;
  Wt[(size_t)j * K + k] = f2bf(W[idx]);
}

extern "C" void kernel_launch(void* const* d_in, const int* in_sizes, int n_in,
                              void* d_out, int out_size, void* d_ws, size_t ws_size,
                              hipStream_t stream)
{
  const float* x0    = (const float*)d_in[0];
  const float* e0    = (const float*)d_in[1];
  const float* a0    = (const float*)d_in[2];
  const float* W_ne  = (const float*)d_in[3];
  const float* b_ne  = (const float*)d_in[4];
  const float* g_e   = (const float*)d_in[5];
  const float* be_e  = (const float*)d_in[6];
  const float* W_ea  = (const float*)d_in[7];
  const float* b_ea  = (const float*)d_in[8];
  const float* g_a   = (const float*)d_in[9];
  const float* be_a  = (const float*)d_in[10];
  const float* W_emp = (const float*)d_in[11];
  const float* b_emp = (const float*)d_in[12];
  const float* g_emp = (const float*)d_in[13];
  const float* be_emp= (const float*)d_in[14];
  const float* W_nmp = (const float*)d_in[15];
  const float* b_nmp = (const float*)d_in[16];
  const float* g_nmp = (const float*)d_in[17];
  const float* be_nmp= (const float*)d_in[18];
  const int* node_batch  = (const int*)d_in[19];
  const int* edge_index  = (const int*)d_in[20];
  const int* edge_batch  = (const int*)d_in[21];
  const int* tb_index    = (const int*)d_in[22];
  const int* angle_batch = (const int*)d_in[23];

  const int N = in_sizes[0] / 128;
  const int E = in_sizes[1] / 64;
  const int A = in_sizes[2] / 64;

  // ---- workspace layout (bytes, 256-aligned) ----
  char* wsp = (char*)d_ws;
  auto alloc = [&](size_t bytes) { char* p = wsp; wsp += (bytes + 255) & ~(size_t)255; return p; };
  unsigned short* eAB  = (unsigned short*)alloc((size_t)E * 64 * 2);   // e intermediate (bf16)
  unsigned short* aAB  = (unsigned short*)alloc((size_t)A * 64 * 2);   // a intermediate (bf16)
  unsigned short* msg  = (unsigned short*)alloc((size_t)A * 64 * 2);   // msg_e / msg_n (CSR-ordered)
  unsigned short* P    = (unsigned short*)alloc((size_t)N * 384 * 2);  // x partials
  unsigned short* PAE  = (unsigned short*)alloc((size_t)E * 256 * 2);  // angle+emp partials
  int* ptr_n  = (int*)alloc((size_t)(N + 1) * 4);
  int* cur_n  = (int*)alloc((size_t)N * 4);
  int* perm_n = (int*)alloc((size_t)E * 4);
  int* ptr_e  = (int*)alloc((size_t)(E + 1) * 4);
  int* cur_e  = (int*)alloc((size_t)E * 4);
  int* perm_e = (int*)alloc((size_t)A * 4);
  int* opos_n = (int*)alloc((size_t)E * 4);
  int* opos_e = (int*)alloc((size_t)A * 4);
  int* bsum   = (int*)alloc(4096 * 4);
  // stats: 8 (layer,stage) pairs + 3 counts, ONE contiguous block, zeroed once.
  float* stats = (float*)alloc((8 * 2 + 3) * NG * 4);
  auto stp = [&](int l, int k) { return stats + (size_t)((l * 4 + k) * 2) * NG; };
  float* cnt_n = stats + 16 * NG;
  float* cnt_e = stats + 17 * NG;
  float* cnt_a = stats + 18 * NG;
  unsigned short* wt_ne  = (unsigned short*)alloc((size_t)2 * 320 * 64 * 2);
  unsigned short* wt_ea  = (unsigned short*)alloc((size_t)2 * 192 * 64 * 2);
  unsigned short* wt_emp = (unsigned short*)alloc((size_t)2 * 192 * 64 * 2);
  unsigned short* wt_nmp = (unsigned short*)alloc((size_t)2 * 320 * 128 * 2);

  float* x_out = (float*)d_out;

  // ---- one-time prep ----
  for (int i = 0; i < 2; ++i) {
    k_wt<<<(320*64 + 255)/256, 256, 0, stream>>>(W_ne  + (size_t)i*320*64,  wt_ne  + (size_t)i*320*64,  320, 64);
    k_wt<<<(192*64 + 255)/256, 256, 0, stream>>>(W_ea  + (size_t)i*192*64,  wt_ea  + (size_t)i*192*64,  192, 64);
    k_wt<<<(192*64 + 255)/256, 256, 0, stream>>>(W_emp + (size_t)i*192*64,  wt_emp + (size_t)i*192*64,  192, 64);
    k_wt<<<(320*128 + 255)/256, 256, 0, stream>>>(W_nmp + (size_t)i*320*128, wt_nmp + (size_t)i*320*128, 320, 128);
  }
  hipMemsetAsync(stats, 0, (8 * 2 + 3) * NG * 4, stream);
  k_count<<<512, 256, 0, stream>>>(node_batch, N, cnt_n);
  k_count<<<512, 256, 0, stream>>>(edge_batch, E, cnt_e);
  k_count<<<512, 256, 0, stream>>>(angle_batch, A, cnt_a);

  // CSR over nodes (dst of edge_index) and edges (dst of threebody) + inverse perms
  hipMemsetAsync(cur_n, 0, (size_t)N * 4, stream);
  hipMemsetAsync(cur_e, 0, (size_t)E * 4, stream);
  k_hist<<<1024, 256, 0, stream>>>(edge_index + E, E, cur_n);
  k_hist<<<1024, 256, 0, stream>>>(tb_index + A, A, cur_e);
  int nbN = (N + 1023) / 1024, nbE = (E + 1023) / 1024;
  k_scan1<<<nbN, 256, 0, stream>>>(cur_n, ptr_n, bsum, N);
  k_scan2<<<1, 256, 0, stream>>>(bsum, nbN, ptr_n + N);
  k_scan3<<<1024, 256, 0, stream>>>(ptr_n, cur_n, bsum, N);
  k_scatter<<<1024, 256, 0, stream>>>(edge_index + E, cur_n, perm_n, E);
  k_invperm<<<1024, 256, 0, stream>>>(perm_n, opos_n, E);
  k_scan1<<<nbE, 256, 0, stream>>>(cur_e, ptr_e, bsum, E);
  k_scan2<<<1, 256, 0, stream>>>(bsum, nbE, ptr_e + E);
  k_scan3<<<1024, 256, 0, stream>>>(ptr_e, cur_e, bsum, E);
  k_scatter<<<1024, 256, 0, stream>>>(tb_index + A, cur_e, perm_e, A);
  k_invperm<<<1024, 256, 0, stream>>>(perm_e, opos_e, A);

  int blkE = (E / 16 + 3) / 4;
  int blkA = (A / 16 + 3) / 4;
  int blkN = (N / 16 + 3) / 4;

  for (int i = 0; i < 2; ++i) {
    // layer input affine sources (nullptr gamma => identity)
    const float* egm = (i == 0) ? nullptr : g_emp;       // afE2 of layer 0
    const float* ebt = (i == 0) ? nullptr : be_emp;
    const float* es1 = (i == 0) ? nullptr : stp(0, 2);
    const float* es2 = (i == 0) ? nullptr : stp(0, 2) + NG;
    const float* agm = (i == 0) ? nullptr : g_a;         // afA1 of layer 0
    const float* abt = (i == 0) ? nullptr : be_a;
    const float* as1 = (i == 0) ? nullptr : stp(0, 1);
    const float* as2 = (i == 0) ? nullptr : stp(0, 1) + NG;

    // 0. dense x-partials (layer 1 applies pending node affine from layer 0)
    if (i == 0)
      k_dense_x<false><<<blkN, 256, 0, stream>>>(x0, node_batch,
          nullptr, nullptr, nullptr, nullptr, nullptr,
          wt_ne, wt_nmp, P, N);
    else
      k_dense_x<true><<<blkN, 256, 0, stream>>>(x_out, node_batch,
          stp(0, 3), stp(0, 3) + NG, cnt_n, g_nmp, be_nmp,
          wt_ne + (size_t)320*64, wt_nmp + (size_t)320*128, P, N);

    // 1. edge stage -> stats st(i,0)
    if (i == 0)
      k_edge<true><<<blkE, 256, 0, stream>>>(P, (const void*)e0, eAB, edge_index, edge_batch,
          es1, es2, cnt_e, egm, ebt,
          wt_ne + (size_t)i*320*64, b_ne + i*64,
          stp(i, 0), stp(i, 0) + NG, E);
    else
      k_edge<false><<<blkE, 256, 0, stream>>>(P, (const void*)eAB, eAB, edge_index, edge_batch,
          es1, es2, cnt_e, egm, ebt,
          wt_ne + (size_t)i*320*64, b_ne + i*64,
          stp(i, 0), stp(i, 0) + NG, E);

    // 1.5 dense angle+emp partials -> PAE (affE1 from st(i,0))
    k_prep_e<<<blkE, 256, 0, stream>>>(eAB, edge_batch,
        stp(i, 0), stp(i, 0) + NG, cnt_e, g_e + i*64, be_e + i*64,
        wt_ea + (size_t)i*192*64, wt_emp + (size_t)i*192*64, PAE, E);

    // 2. angle stage -> stats st(i,1)
    if (i == 0)
      k_angle<true><<<blkA, 256, 0, stream>>>(PAE, (const void*)a0, aAB, tb_index, angle_batch,
          as1, as2, cnt_a, agm, abt,
          wt_ea + (size_t)i*192*64, b_ea + i*64,
          stp(i, 1), stp(i, 1) + NG, A);
    else
      k_angle<false><<<blkA, 256, 0, stream>>>(PAE, (const void*)aAB, aAB, tb_index, angle_batch,
          as1, as2, cnt_a, agm, abt,
          wt_ea + (size_t)i*192*64, b_ea + i*64,
          stp(i, 1), stp(i, 1) + NG, A);

    // 3. emp finish -> msg (CSR order, affA1 from st(i,1)); streaming reduce -> st(i,2)
    k_fin_emp<<<blkA, 256, 0, stream>>>(PAE, aAB, tb_index, angle_batch, opos_e,
        stp(i, 1), stp(i, 1) + NG, cnt_a, g_a + i*64, be_a + i*64,
        wt_emp + (size_t)i*192*64, b_emp + i*64, msg, A);
    k_red_e<<<2048, 256, 0, stream>>>(msg, eAB, eAB, ptr_e, edge_batch,
        stp(i, 0), stp(i, 0) + NG, cnt_e, g_e + i*64, be_e + i*64,
        stp(i, 2), stp(i, 2) + NG, E);

    // 4. nmp finish -> msg (CSR order, affE2 from st(i,2)); streaming reduce -> st(i,3)
    k_fin_nmp<<<blkE, 256, 0, stream>>>(P, eAB, edge_index, edge_batch, opos_n,
        stp(i, 2), stp(i, 2) + NG, cnt_e, g_emp + i*64, be_emp + i*64,
        wt_nmp + (size_t)i*320*128, b_nmp + i*128, msg, E);
    if (i == 0)
      k_red_n<false><<<2048, 256, 0, stream>>>(msg, x0, x_out, ptr_n, node_batch,
          nullptr, nullptr, nullptr, nullptr, nullptr,
          stp(i, 3), stp(i, 3) + NG, N);
    else
      k_red_n<true><<<2048, 256, 0, stream>>>(msg, x_out, x_out, ptr_n, node_batch,
          stp(0, 3), stp(0, 3) + NG, cnt_n, g_nmp, be_nmp,
          stp(i, 3), stp(i, 3) + NG, N);
  }

  // final normalize of x (layer-1 node affine)
  k_apply<<<2048, 256, 0, stream>>>(x_out, node_batch,
      stp(1, 3), stp(1, 3) + NG, cnt_n, g_nmp + 128, be_nmp + 128, N);
}